// Round 2
// baseline (4158.041 us; speedup 1.0000x reference)
//
#include <hip/hip_runtime.h>
#include <hip/hip_bf16.h>

#define NNODES 50000
#define NEDGES 800000
#define ETOT   (NEDGES + NNODES)
#define FIN    256
#define HEADS  4
#define C1     32
#define D1     128   // HEADS*C1
#define C2     40
#define D2     160   // HEADS*C2

// monotonic float<->uint encoding for atomicMax
__device__ __forceinline__ unsigned encf(float f) {
    unsigned u = __float_as_uint(f);
    return (u >> 31) ? ~u : (u | 0x80000000u);
}
__device__ __forceinline__ float decf(unsigned k) {
    return __uint_as_float((k >> 31) ? (k & 0x7fffffffu) : ~k);
}

__device__ __forceinline__ float wave_sum(float v) {
    #pragma unroll
    for (int m = 32; m > 0; m >>= 1) v += __shfl_xor(v, m, 64);
    return v;
}
__device__ __forceinline__ float wave_max(float v) {
    #pragma unroll
    for (int m = 32; m > 0; m >>= 1) v = fmaxf(v, __shfl_xor(v, m, 64));
    return v;
}

// ---------------- GEMM: Out[M,Ncol] = A[M,K] @ W[K,Ncol], all f32
// block 256 threads; tile BM=256 x BN=32 x BK=32; micro 8 rows x 4 cols / thread
__global__ __launch_bounds__(256) void gemm_tile(const float* __restrict__ A,
                                                 const float* __restrict__ W,
                                                 float* __restrict__ Out,
                                                 int M, int K, int Ncol) {
    __shared__ float As[256][33];
    __shared__ float Ws[32][33];
    const int t = threadIdx.x;
    const int rbase = blockIdx.x * 256;
    const int cbase = blockIdx.y * 32;
    const int tx = t & 7, ty = t >> 3;

    float acc[8][4];
    #pragma unroll
    for (int i = 0; i < 8; i++)
        #pragma unroll
        for (int j = 0; j < 4; j++) acc[i][j] = 0.f;

    const int ksteps = K >> 5;
    for (int ks = 0; ks < ksteps; ks++) {
        const int kbase = ks << 5;
        #pragma unroll
        for (int pass = 0; pass < 8; pass++) {
            int row = pass * 32 + (t >> 3);
            int chunk = t & 7;
            int gr = rbase + row;
            float4 v = make_float4(0.f, 0.f, 0.f, 0.f);
            if (gr < M) v = *(const float4*)(A + (size_t)gr * K + kbase + chunk * 4);
            As[row][chunk * 4 + 0] = v.x; As[row][chunk * 4 + 1] = v.y;
            As[row][chunk * 4 + 2] = v.z; As[row][chunk * 4 + 3] = v.w;
        }
        {
            int row = t >> 3, chunk = t & 7;
            float4 v = *(const float4*)(W + (size_t)(kbase + row) * Ncol + cbase + chunk * 4);
            Ws[row][chunk * 4 + 0] = v.x; Ws[row][chunk * 4 + 1] = v.y;
            Ws[row][chunk * 4 + 2] = v.z; Ws[row][chunk * 4 + 3] = v.w;
        }
        __syncthreads();
        #pragma unroll
        for (int kk = 0; kk < 32; kk++) {
            float w0 = Ws[kk][tx * 4 + 0], w1 = Ws[kk][tx * 4 + 1];
            float w2 = Ws[kk][tx * 4 + 2], w3 = Ws[kk][tx * 4 + 3];
            #pragma unroll
            for (int rr = 0; rr < 8; rr++) {
                float a = As[ty * 8 + rr][kk];
                acc[rr][0] += a * w0; acc[rr][1] += a * w1;
                acc[rr][2] += a * w2; acc[rr][3] += a * w3;
            }
        }
        __syncthreads();
    }
    #pragma unroll
    for (int rr = 0; rr < 8; rr++) {
        int r = rbase + ty * 8 + rr;
        if (r < M) {
            float4 v = make_float4(acc[rr][0], acc[rr][1], acc[rr][2], acc[rr][3]);
            *(float4*)(Out + (size_t)r * Ncol + cbase + tx * 4) = v;
        }
    }
}

// ---------------- per-(node,head) attention dots
__global__ void node_dots(const float* __restrict__ Hh, const float* __restrict__ a_s,
                          const float* __restrict__ a_d, float* __restrict__ ssrc,
                          float* __restrict__ sdst, int C, int Dfull) {
    int t = blockIdx.x * blockDim.x + threadIdx.x;
    if (t >= NNODES * HEADS) return;
    int n = t >> 2, h = t & 3;
    const float* hp = Hh + (size_t)n * Dfull + h * C;
    float s1 = 0.f, s2 = 0.f;
    for (int c = 0; c < C; c++) {
        float v = hp[c];
        s1 += v * a_s[h * C + c];
        s2 += v * a_d[h * C + c];
    }
    ssrc[t] = s1; sdst[t] = s2;
}

// ---------------- edge pass 1: segment max over dst (encoded atomicMax)
__global__ void edge_max_k(const int* __restrict__ ei, const float* __restrict__ ssrc,
                           const float* __restrict__ sdst, unsigned* __restrict__ mkey) {
    int t = blockIdx.x * blockDim.x + threadIdx.x;
    if (t >= ETOT) return;
    int s, d;
    if (t < NEDGES) { s = ei[t]; d = ei[NEDGES + t]; } else { s = t - NEDGES; d = s; }
    #pragma unroll
    for (int h = 0; h < HEADS; h++) {
        float e = ssrc[s * 4 + h] + sdst[d * 4 + h];
        e = e > 0.f ? e : 0.2f * e;
        atomicMax(&mkey[d * 4 + h], encf(e));
    }
}

// ---------------- edge pass 2: p = exp(e - m), denom += p
__global__ void edge_exp_k(const int* __restrict__ ei, const float* __restrict__ ssrc,
                           const float* __restrict__ sdst, const unsigned* __restrict__ mkey,
                           float* __restrict__ denom, float* __restrict__ pbuf) {
    int t = blockIdx.x * blockDim.x + threadIdx.x;
    if (t >= ETOT) return;
    int s, d;
    if (t < NEDGES) { s = ei[t]; d = ei[NEDGES + t]; } else { s = t - NEDGES; d = s; }
    #pragma unroll
    for (int h = 0; h < HEADS; h++) {
        float e = ssrc[s * 4 + h] + sdst[d * 4 + h];
        e = e > 0.f ? e : 0.2f * e;
        float pv = expf(e - decf(mkey[d * 4 + h]));
        pbuf[(size_t)t * 4 + h] = pv;
        atomicAdd(&denom[d * 4 + h], pv);
    }
}

// ---------------- edge pass 3: out[dst] += h[src] * alpha  (thread = edge,head,4ch)
__global__ void edge_scatter(const int* __restrict__ ei, const float* __restrict__ Hh,
                             const float* __restrict__ pbuf, const float* __restrict__ denom,
                             float* __restrict__ Outp, int C, int Dfull, int qmax, long total) {
    long t = (long)blockIdx.x * blockDim.x + threadIdx.x;
    if (t >= total) return;
    int per_edge = HEADS * qmax;
    int e = (int)(t / per_edge);
    int rem = (int)(t % per_edge);
    int h = rem / qmax, q = rem - h * qmax;
    int s, d;
    if (e < NEDGES) { s = ei[e]; d = ei[NEDGES + e]; } else { s = e - NEDGES; d = s; }
    float alpha = pbuf[(size_t)e * 4 + h] / (denom[d * 4 + h] + 1e-16f);
    float4 hv = *(const float4*)(Hh + (size_t)s * Dfull + h * C + q * 4);
    float* op = Outp + (size_t)d * Dfull + h * C + q * 4;
    atomicAdd(op + 0, hv.x * alpha);
    atomicAdd(op + 1, hv.y * alpha);
    atomicAdd(op + 2, hv.z * alpha);
    atomicAdd(op + 3, hv.w * alpha);
}

// ---------------- bias + ELU + LayerNorm(128) in place, wave per node
__global__ __launch_bounds__(256) void elu_ln_k(float* __restrict__ BO, const float* __restrict__ b1,
                                                const float* __restrict__ g, const float* __restrict__ be) {
    int node = blockIdx.x * 4 + (threadIdx.x >> 6);
    int lane = threadIdx.x & 63;
    float* row = BO + (size_t)node * D1;
    float v0 = row[lane] + b1[lane];
    float v1 = row[lane + 64] + b1[lane + 64];
    v0 = v0 > 0.f ? v0 : expf(v0) - 1.f;
    v1 = v1 > 0.f ? v1 : expf(v1) - 1.f;
    float mu = wave_sum(v0 + v1) * (1.f / 128.f);
    float d0 = v0 - mu, d1 = v1 - mu;
    float var = wave_sum(d0 * d0 + d1 * d1) * (1.f / 128.f);
    float rs = rsqrtf(var + 1e-5f);
    row[lane] = d0 * rs * g[lane] + be[lane];
    row[lane + 64] = d1 * rs * g[lane + 64] + be[lane + 64];
}

// ---------------- head-mean + bias + LayerNorm(40) + log_softmax -> f32 out
__global__ __launch_bounds__(256) void final_k(const float* __restrict__ BO, const float* __restrict__ b2,
                                               const float* __restrict__ g, const float* __restrict__ be,
                                               float* __restrict__ out) {
    int node = blockIdx.x * 4 + (threadIdx.x >> 6);
    int lane = threadIdx.x & 63;
    bool act = lane < 40;
    int c = act ? lane : 0;
    const float* row = BO + (size_t)node * D2;
    float o = 0.f;
    if (act)
        o = 0.25f * (row[c] + row[40 + c] + row[80 + c] + row[120 + c]) + b2[c];
    float mu = wave_sum(act ? o : 0.f) * (1.f / 40.f);
    float dv = act ? o - mu : 0.f;
    float var = wave_sum(dv * dv) * (1.f / 40.f);
    float rs = rsqrtf(var + 1e-5f);
    float y = act ? dv * rs * g[c] + be[c] : -1e30f;
    float mx = wave_max(y);
    float ex = act ? expf(y - mx) : 0.f;
    float lse = logf(wave_sum(ex));
    if (act) out[(size_t)node * 40 + c] = y - mx - lse;
}

extern "C" void kernel_launch(void* const* d_in, const int* in_sizes, int n_in,
                              void* d_out, int out_size, void* d_ws, size_t ws_size,
                              hipStream_t stream) {
    const float* x   = (const float*)d_in[0];
    const int*   ei  = (const int*)d_in[1];
    const float* W1  = (const float*)d_in[2];
    const float* as1 = (const float*)d_in[3];
    const float* ad1 = (const float*)d_in[4];
    const float* b1  = (const float*)d_in[5];
    const float* W2  = (const float*)d_in[6];
    const float* as2 = (const float*)d_in[7];
    const float* ad2 = (const float*)d_in[8];
    const float* b2  = (const float*)d_in[9];
    const float* g0  = (const float*)d_in[10];
    const float* be0 = (const float*)d_in[11];
    const float* g1  = (const float*)d_in[12];
    const float* be1 = (const float*)d_in[13];

    float* ws = (float*)d_ws;
    float*    BH    = ws;                    // N*160 f32
    float*    BO    = ws + 8000000;          // N*160 f32
    float*    ssrc  = ws + 16000000;         // N*4
    float*    sdst  = ws + 16200000;         // N*4
    unsigned* mkey  = (unsigned*)(ws + 16400000);  // N*4
    float*    denom = ws + 16600000;         // N*4
    float*    pbuf  = ws + 16800000;         // ETOT*4 = 3.4M

    const int eb = (ETOT + 255) / 256;

    // ================= layer 1 =================
    hipMemsetAsync(BO, 0, (size_t)NNODES * D1 * sizeof(float), stream);
    hipMemsetAsync(mkey, 0, (size_t)NNODES * 4 * 4, stream);
    hipMemsetAsync(denom, 0, (size_t)NNODES * 4 * 4, stream);

    dim3 gg1((NNODES + 255) / 256, D1 / 32);
    gemm_tile<<<gg1, 256, 0, stream>>>(x, W1, BH, NNODES, FIN, D1);
    node_dots<<<(NNODES * 4 + 255) / 256, 256, 0, stream>>>(BH, as1, ad1, ssrc, sdst, C1, D1);
    edge_max_k<<<eb, 256, 0, stream>>>(ei, ssrc, sdst, mkey);
    edge_exp_k<<<eb, 256, 0, stream>>>(ei, ssrc, sdst, mkey, denom, pbuf);
    long tot1 = (long)ETOT * HEADS * (C1 / 4);
    edge_scatter<<<(int)((tot1 + 255) / 256), 256, 0, stream>>>(ei, BH, pbuf, denom, BO, C1, D1, C1 / 4, tot1);
    elu_ln_k<<<NNODES / 4, 256, 0, stream>>>(BO, b1, g0, be0);

    // ================= layer 2 =================
    dim3 gg2((NNODES + 255) / 256, D2 / 32);
    gemm_tile<<<gg2, 256, 0, stream>>>(BO, W2, BH, NNODES, D1, D2);
    node_dots<<<(NNODES * 4 + 255) / 256, 256, 0, stream>>>(BH, as2, ad2, ssrc, sdst, C2, D2);
    hipMemsetAsync(BO, 0, (size_t)NNODES * D2 * sizeof(float), stream);
    hipMemsetAsync(mkey, 0, (size_t)NNODES * 4 * 4, stream);
    hipMemsetAsync(denom, 0, (size_t)NNODES * 4 * 4, stream);
    edge_max_k<<<eb, 256, 0, stream>>>(ei, ssrc, sdst, mkey);
    edge_exp_k<<<eb, 256, 0, stream>>>(ei, ssrc, sdst, mkey, denom, pbuf);
    long tot2 = (long)ETOT * HEADS * (C2 / 4);
    edge_scatter<<<(int)((tot2 + 255) / 256), 256, 0, stream>>>(ei, BH, pbuf, denom, BO, C2, D2, C2 / 4, tot2);
    final_k<<<NNODES / 4, 256, 0, stream>>>(BO, b2, g1, be1, (float*)d_out);
}

// Round 3
// 832.046 us; speedup vs baseline: 4.9974x; 4.9974x over previous
//
#include <hip/hip_runtime.h>
#include <hip/hip_bf16.h>

#define NNODES 50000
#define NEDGES 800000
#define ETOT   (NEDGES + NNODES)
#define FIN    256
#define HEADS  4
#define C1     32
#define D1     128   // HEADS*C1
#define C2     40
#define D2     160   // HEADS*C2

__device__ __forceinline__ float wave_sum(float v) {
    #pragma unroll
    for (int m = 32; m > 0; m >>= 1) v += __shfl_xor(v, m, 64);
    return v;
}
__device__ __forceinline__ float wave_max(float v) {
    #pragma unroll
    for (int m = 32; m > 0; m >>= 1) v = fmaxf(v, __shfl_xor(v, m, 64));
    return v;
}

// ---------------- GEMM: Out[M,Ncol] = A[M,K] @ W[K,Ncol], all f32
__global__ __launch_bounds__(256) void gemm_tile(const float* __restrict__ A,
                                                 const float* __restrict__ W,
                                                 float* __restrict__ Out,
                                                 int M, int K, int Ncol) {
    __shared__ float As[256][33];
    __shared__ float Ws[32][33];
    const int t = threadIdx.x;
    const int rbase = blockIdx.x * 256;
    const int cbase = blockIdx.y * 32;
    const int tx = t & 7, ty = t >> 3;

    float acc[8][4];
    #pragma unroll
    for (int i = 0; i < 8; i++)
        #pragma unroll
        for (int j = 0; j < 4; j++) acc[i][j] = 0.f;

    const int ksteps = K >> 5;
    for (int ks = 0; ks < ksteps; ks++) {
        const int kbase = ks << 5;
        #pragma unroll
        for (int pass = 0; pass < 8; pass++) {
            int row = pass * 32 + (t >> 3);
            int chunk = t & 7;
            int gr = rbase + row;
            float4 v = make_float4(0.f, 0.f, 0.f, 0.f);
            if (gr < M) v = *(const float4*)(A + (size_t)gr * K + kbase + chunk * 4);
            As[row][chunk * 4 + 0] = v.x; As[row][chunk * 4 + 1] = v.y;
            As[row][chunk * 4 + 2] = v.z; As[row][chunk * 4 + 3] = v.w;
        }
        {
            int row = t >> 3, chunk = t & 7;
            float4 v = *(const float4*)(W + (size_t)(kbase + row) * Ncol + cbase + chunk * 4);
            Ws[row][chunk * 4 + 0] = v.x; Ws[row][chunk * 4 + 1] = v.y;
            Ws[row][chunk * 4 + 2] = v.z; Ws[row][chunk * 4 + 3] = v.w;
        }
        __syncthreads();
        #pragma unroll
        for (int kk = 0; kk < 32; kk++) {
            float w0 = Ws[kk][tx * 4 + 0], w1 = Ws[kk][tx * 4 + 1];
            float w2 = Ws[kk][tx * 4 + 2], w3 = Ws[kk][tx * 4 + 3];
            #pragma unroll
            for (int rr = 0; rr < 8; rr++) {
                float a = As[ty * 8 + rr][kk];
                acc[rr][0] += a * w0; acc[rr][1] += a * w1;
                acc[rr][2] += a * w2; acc[rr][3] += a * w3;
            }
        }
        __syncthreads();
    }
    #pragma unroll
    for (int rr = 0; rr < 8; rr++) {
        int r = rbase + ty * 8 + rr;
        if (r < M) {
            float4 v = make_float4(acc[rr][0], acc[rr][1], acc[rr][2], acc[rr][3]);
            *(float4*)(Out + (size_t)r * Ncol + cbase + tx * 4) = v;
        }
    }
}

// ---------------- per-(node,head) attention dots
__global__ void node_dots(const float* __restrict__ Hh, const float* __restrict__ a_s,
                          const float* __restrict__ a_d, float* __restrict__ ssrc,
                          float* __restrict__ sdst, int C, int Dfull) {
    int t = blockIdx.x * blockDim.x + threadIdx.x;
    if (t >= NNODES * HEADS) return;
    int n = t >> 2, h = t & 3;
    const float* hp = Hh + (size_t)n * Dfull + h * C;
    float s1 = 0.f, s2 = 0.f;
    for (int c = 0; c < C; c++) {
        float v = hp[c];
        s1 += v * a_s[h * C + c];
        s2 += v * a_d[h * C + c];
    }
    ssrc[t] = s1; sdst[t] = s2;
}

// ---------------- CSR build: histogram of dst
__global__ void count_k(const int* __restrict__ ei, int* __restrict__ counts) {
    int t = blockIdx.x * blockDim.x + threadIdx.x;
    if (t >= ETOT) return;
    int d = (t < NEDGES) ? ei[NEDGES + t] : (t - NEDGES);
    atomicAdd(&counts[d], 1);
}

// single-block hierarchical exclusive scan of counts[NNODES] -> rowptr[NNODES+1]
__global__ __launch_bounds__(1024) void scan_k(const int* __restrict__ counts, int* __restrict__ rowptr) {
    __shared__ int wsum[16];
    __shared__ int srun;
    const int t = threadIdx.x;
    const int lane = t & 63, wid = t >> 6;
    if (t == 0) srun = 0;
    __syncthreads();
    for (int base = 0; base < NNODES; base += 1024) {
        int idx = base + t;
        int v = (idx < NNODES) ? counts[idx] : 0;
        int x = v;
        #pragma unroll
        for (int off = 1; off < 64; off <<= 1) {
            int y = __shfl_up(x, off, 64);
            if (lane >= off) x += y;
        }
        if (lane == 63) wsum[wid] = x;
        __syncthreads();
        if (wid == 0) {
            int w = (lane < 16) ? wsum[lane] : 0;
            #pragma unroll
            for (int off = 1; off < 16; off <<= 1) {
                int y = __shfl_up(w, off, 64);
                if (lane >= off) w += y;
            }
            if (lane < 16) wsum[lane] = w;
        }
        __syncthreads();
        int wbase = (wid > 0) ? wsum[wid - 1] : 0;
        int run = srun;
        if (idx < NNODES) rowptr[idx] = run + wbase + x - v;
        __syncthreads();
        if (t == 1023) srun = run + wsum[15];
        __syncthreads();
    }
    if (t == 0) rowptr[NNODES] = srun;
}

// fill CSR: esrc[rowptr[d] + pos] = s
__global__ void fill_k(const int* __restrict__ ei, const int* __restrict__ rowptr,
                       int* __restrict__ cursor, int* __restrict__ esrc) {
    int t = blockIdx.x * blockDim.x + threadIdx.x;
    if (t >= ETOT) return;
    int s, d;
    if (t < NEDGES) { s = ei[t]; d = ei[NEDGES + t]; } else { s = t - NEDGES; d = s; }
    int pos = atomicAdd(&cursor[d], 1);
    esrc[rowptr[d] + pos] = s;
}

// ---------------- layer-1 gather: wave per node, online softmax, lane = 2 channels
__global__ __launch_bounds__(256) void gat_gather1(const int* __restrict__ rowptr,
                                                   const int* __restrict__ esrc,
                                                   const float* __restrict__ BH,
                                                   const float* __restrict__ ssrc,
                                                   const float* __restrict__ sdst,
                                                   float* __restrict__ BO) {
    int node = blockIdx.x * 4 + (threadIdx.x >> 6);
    if (node >= NNODES) return;
    int lane = threadIdx.x & 63;
    int h0 = lane >> 5, h1 = h0 + 2;   // chan0 = lane (heads 0/1), chan1 = lane+64 (heads 2/3)
    float sd0 = sdst[node * 4 + h0];
    float sd1 = sdst[node * 4 + h1];
    int beg = rowptr[node], end = rowptr[node + 1];
    float m0 = -INFINITY, m1 = -INFINITY;
    float den0 = 0.f, den1 = 0.f, acc0 = 0.f, acc1 = 0.f;
    for (int i = beg; i < end; i++) {
        int s = esrc[i];
        const float* hp = BH + (size_t)s * D1;
        float e0 = ssrc[s * 4 + h0] + sd0; e0 = e0 > 0.f ? e0 : 0.2f * e0;
        float e1 = ssrc[s * 4 + h1] + sd1; e1 = e1 > 0.f ? e1 : 0.2f * e1;
        float nm0 = fmaxf(m0, e0), nm1 = fmaxf(m1, e1);
        float sc0 = expf(m0 - nm0), sc1 = expf(m1 - nm1);
        float p0 = expf(e0 - nm0),  p1 = expf(e1 - nm1);
        acc0 = acc0 * sc0 + p0 * hp[lane];
        acc1 = acc1 * sc1 + p1 * hp[lane + 64];
        den0 = den0 * sc0 + p0;
        den1 = den1 * sc1 + p1;
        m0 = nm0; m1 = nm1;
    }
    BO[(size_t)node * D1 + lane]      = acc0 / (den0 + 1e-16f);
    BO[(size_t)node * D1 + lane + 64] = acc1 / (den1 + 1e-16f);
}

// ---------------- layer-2 gather: wave per node, D2=160, lane = up to 3 channels
__global__ __launch_bounds__(256) void gat_gather2(const int* __restrict__ rowptr,
                                                   const int* __restrict__ esrc,
                                                   const float* __restrict__ BH,
                                                   const float* __restrict__ ssrc,
                                                   const float* __restrict__ sdst,
                                                   float* __restrict__ BO) {
    int node = blockIdx.x * 4 + (threadIdx.x >> 6);
    if (node >= NNODES) return;
    int lane = threadIdx.x & 63;
    float sd0 = sdst[node * 4 + 0], sd1 = sdst[node * 4 + 1];
    float sd2 = sdst[node * 4 + 2], sd3 = sdst[node * 4 + 3];
    int beg = rowptr[node], end = rowptr[node + 1];
    float m0 = -INFINITY, m1 = -INFINITY, m2 = -INFINITY, m3 = -INFINITY;
    float d0 = 0.f, d1 = 0.f, d2 = 0.f, d3 = 0.f;
    float acc0 = 0.f, acc1 = 0.f, acc2 = 0.f;
    bool lo = lane < 40;            // chan0 = lane: head 0 or 1
    bool amid = lane < 16;          // chan1 = lane+64: head 1 (64..79), 2 (80..119), 3 (120..127)
    bool bmid = lane < 56;
    bool third = lane < 32;         // chan2 = lane+128: head 3
    for (int i = beg; i < end; i++) {
        int s = esrc[i];
        const float* hp = BH + (size_t)s * D2;
        const float* sp = ssrc + s * 4;
        float e0 = sp[0] + sd0; e0 = e0 > 0.f ? e0 : 0.2f * e0;
        float e1 = sp[1] + sd1; e1 = e1 > 0.f ? e1 : 0.2f * e1;
        float e2 = sp[2] + sd2; e2 = e2 > 0.f ? e2 : 0.2f * e2;
        float e3 = sp[3] + sd3; e3 = e3 > 0.f ? e3 : 0.2f * e3;
        float nm0 = fmaxf(m0, e0), nm1 = fmaxf(m1, e1);
        float nm2 = fmaxf(m2, e2), nm3 = fmaxf(m3, e3);
        float s0 = expf(m0 - nm0), s1 = expf(m1 - nm1);
        float s2 = expf(m2 - nm2), s3 = expf(m3 - nm3);
        float p0 = expf(e0 - nm0), p1 = expf(e1 - nm1);
        float p2 = expf(e2 - nm2), p3 = expf(e3 - nm3);
        d0 = d0 * s0 + p0; d1 = d1 * s1 + p1;
        d2 = d2 * s2 + p2; d3 = d3 * s3 + p3;
        m0 = nm0; m1 = nm1; m2 = nm2; m3 = nm3;
        float scA = lo ? s0 : s1,  pA = lo ? p0 : p1;
        float scB = amid ? s1 : (bmid ? s2 : s3);
        float pB  = amid ? p1 : (bmid ? p2 : p3);
        acc0 = acc0 * scA + pA * hp[lane];
        acc1 = acc1 * scB + pB * hp[lane + 64];
        if (third) acc2 = acc2 * s3 + p3 * hp[lane + 128];
    }
    float denA = lo ? d0 : d1;
    float denB = amid ? d1 : (bmid ? d2 : d3);
    BO[(size_t)node * D2 + lane]      = acc0 / (denA + 1e-16f);
    BO[(size_t)node * D2 + lane + 64] = acc1 / (denB + 1e-16f);
    if (third) BO[(size_t)node * D2 + lane + 128] = acc2 / (d3 + 1e-16f);
}

// ---------------- bias + ELU + LayerNorm(128) in place, wave per node
__global__ __launch_bounds__(256) void elu_ln_k(float* __restrict__ BO, const float* __restrict__ b1,
                                                const float* __restrict__ g, const float* __restrict__ be) {
    int node = blockIdx.x * 4 + (threadIdx.x >> 6);
    int lane = threadIdx.x & 63;
    float* row = BO + (size_t)node * D1;
    float v0 = row[lane] + b1[lane];
    float v1 = row[lane + 64] + b1[lane + 64];
    v0 = v0 > 0.f ? v0 : expf(v0) - 1.f;
    v1 = v1 > 0.f ? v1 : expf(v1) - 1.f;
    float mu = wave_sum(v0 + v1) * (1.f / 128.f);
    float d0 = v0 - mu, d1 = v1 - mu;
    float var = wave_sum(d0 * d0 + d1 * d1) * (1.f / 128.f);
    float rs = rsqrtf(var + 1e-5f);
    row[lane] = d0 * rs * g[lane] + be[lane];
    row[lane + 64] = d1 * rs * g[lane + 64] + be[lane + 64];
}

// ---------------- head-mean + bias + LayerNorm(40) + log_softmax -> f32 out
__global__ __launch_bounds__(256) void final_k(const float* __restrict__ BO, const float* __restrict__ b2,
                                               const float* __restrict__ g, const float* __restrict__ be,
                                               float* __restrict__ out) {
    int node = blockIdx.x * 4 + (threadIdx.x >> 6);
    int lane = threadIdx.x & 63;
    bool act = lane < 40;
    int c = act ? lane : 0;
    const float* row = BO + (size_t)node * D2;
    float o = 0.f;
    if (act)
        o = 0.25f * (row[c] + row[40 + c] + row[80 + c] + row[120 + c]) + b2[c];
    float mu = wave_sum(act ? o : 0.f) * (1.f / 40.f);
    float dv = act ? o - mu : 0.f;
    float var = wave_sum(dv * dv) * (1.f / 40.f);
    float rs = rsqrtf(var + 1e-5f);
    float y = act ? dv * rs * g[c] + be[c] : -1e30f;
    float mx = wave_max(y);
    float ex = act ? expf(y - mx) : 0.f;
    float lse = logf(wave_sum(ex));
    if (act) out[(size_t)node * 40 + c] = y - mx - lse;
}

extern "C" void kernel_launch(void* const* d_in, const int* in_sizes, int n_in,
                              void* d_out, int out_size, void* d_ws, size_t ws_size,
                              hipStream_t stream) {
    const float* x   = (const float*)d_in[0];
    const int*   ei  = (const int*)d_in[1];
    const float* W1  = (const float*)d_in[2];
    const float* as1 = (const float*)d_in[3];
    const float* ad1 = (const float*)d_in[4];
    const float* b1  = (const float*)d_in[5];
    const float* W2  = (const float*)d_in[6];
    const float* as2 = (const float*)d_in[7];
    const float* ad2 = (const float*)d_in[8];
    const float* b2  = (const float*)d_in[9];
    const float* g0  = (const float*)d_in[10];
    const float* be0 = (const float*)d_in[11];
    const float* g1  = (const float*)d_in[12];
    const float* be1 = (const float*)d_in[13];

    float* ws = (float*)d_ws;
    float* BH   = ws;                          // N*160 f32
    float* BO   = ws + 8000000;                // N*160 f32
    float* ssrc = ws + 16000000;               // N*4
    float* sdst = ws + 16200000;               // N*4
    int*   counts = (int*)(ws + 16400000);     // N
    int*   rowptr = (int*)(ws + 16450000);     // N+1
    int*   cursor = (int*)(ws + 16500008);     // N
    int*   esrc   = (int*)(ws + 16550008);     // ETOT

    const int eb = (ETOT + 255) / 256;
    const int nb4 = (NNODES + 3) / 4;

    // ---- CSR build (graph shared by both layers) ----
    hipMemsetAsync(counts, 0, NNODES * sizeof(int), stream);
    hipMemsetAsync(cursor, 0, NNODES * sizeof(int), stream);
    count_k<<<eb, 256, 0, stream>>>(ei, counts);
    scan_k<<<1, 1024, 0, stream>>>(counts, rowptr);
    fill_k<<<eb, 256, 0, stream>>>(ei, rowptr, cursor, esrc);

    // ================= layer 1 =================
    dim3 gg1((NNODES + 255) / 256, D1 / 32);
    gemm_tile<<<gg1, 256, 0, stream>>>(x, W1, BH, NNODES, FIN, D1);
    node_dots<<<(NNODES * 4 + 255) / 256, 256, 0, stream>>>(BH, as1, ad1, ssrc, sdst, C1, D1);
    gat_gather1<<<nb4, 256, 0, stream>>>(rowptr, esrc, BH, ssrc, sdst, BO);
    elu_ln_k<<<nb4, 256, 0, stream>>>(BO, b1, g0, be0);

    // ================= layer 2 =================
    dim3 gg2((NNODES + 255) / 256, D2 / 32);
    gemm_tile<<<gg2, 256, 0, stream>>>(BO, W2, BH, NNODES, D1, D2);
    node_dots<<<(NNODES * 4 + 255) / 256, 256, 0, stream>>>(BH, as2, ad2, ssrc, sdst, C2, D2);
    gat_gather2<<<nb4, 256, 0, stream>>>(rowptr, esrc, BH, ssrc, sdst, BO);
    final_k<<<nb4, 256, 0, stream>>>(BO, b2, g1, be1, (float*)d_out);
}

// Round 4
// 686.600 us; speedup vs baseline: 6.0560x; 1.2118x over previous
//
#include <hip/hip_runtime.h>
#include <hip/hip_bf16.h>
#include <hip/hip_fp16.h>

#define NNODES 50000
#define NEDGES 800000
#define ETOT   (NEDGES + NNODES)
#define FIN    256
#define HEADS  4
#define C1     32
#define D1     128   // HEADS*C1
#define C2     40
#define D2     160   // HEADS*C2

typedef unsigned short u16;

__device__ __forceinline__ float wave_sum(float v) {
    #pragma unroll
    for (int m = 32; m > 0; m >>= 1) v += __shfl_xor(v, m, 64);
    return v;
}
__device__ __forceinline__ float wave_max(float v) {
    #pragma unroll
    for (int m = 32; m > 0; m >>= 1) v = fmaxf(v, __shfl_xor(v, m, 64));
    return v;
}
__device__ __forceinline__ float leaky(float x) { return fmaxf(x, 0.2f * x); }

__device__ __forceinline__ float2 unpack_h2(unsigned u) {
    union { unsigned u; __half2 h; } c; c.u = u;
    return __half22float2(c.h);
}

// ---------------- GEMM: Out[M,Ncol] = A[M,K] @ W[K,Ncol], all f32
__global__ __launch_bounds__(256) void gemm_tile(const float* __restrict__ A,
                                                 const float* __restrict__ W,
                                                 float* __restrict__ Out,
                                                 int M, int K, int Ncol) {
    __shared__ float As[256][33];
    __shared__ float Ws[32][33];
    const int t = threadIdx.x;
    const int rbase = blockIdx.x * 256;
    const int cbase = blockIdx.y * 32;
    const int tx = t & 7, ty = t >> 3;

    float acc[8][4];
    #pragma unroll
    for (int i = 0; i < 8; i++)
        #pragma unroll
        for (int j = 0; j < 4; j++) acc[i][j] = 0.f;

    const int ksteps = K >> 5;
    for (int ks = 0; ks < ksteps; ks++) {
        const int kbase = ks << 5;
        #pragma unroll
        for (int pass = 0; pass < 8; pass++) {
            int row = pass * 32 + (t >> 3);
            int chunk = t & 7;
            int gr = rbase + row;
            float4 v = make_float4(0.f, 0.f, 0.f, 0.f);
            if (gr < M) v = *(const float4*)(A + (size_t)gr * K + kbase + chunk * 4);
            As[row][chunk * 4 + 0] = v.x; As[row][chunk * 4 + 1] = v.y;
            As[row][chunk * 4 + 2] = v.z; As[row][chunk * 4 + 3] = v.w;
        }
        {
            int row = t >> 3, chunk = t & 7;
            float4 v = *(const float4*)(W + (size_t)(kbase + row) * Ncol + cbase + chunk * 4);
            Ws[row][chunk * 4 + 0] = v.x; Ws[row][chunk * 4 + 1] = v.y;
            Ws[row][chunk * 4 + 2] = v.z; Ws[row][chunk * 4 + 3] = v.w;
        }
        __syncthreads();
        #pragma unroll
        for (int kk = 0; kk < 32; kk++) {
            float w0 = Ws[kk][tx * 4 + 0], w1 = Ws[kk][tx * 4 + 1];
            float w2 = Ws[kk][tx * 4 + 2], w3 = Ws[kk][tx * 4 + 3];
            #pragma unroll
            for (int rr = 0; rr < 8; rr++) {
                float a = As[ty * 8 + rr][kk];
                acc[rr][0] += a * w0; acc[rr][1] += a * w1;
                acc[rr][2] += a * w2; acc[rr][3] += a * w3;
            }
        }
        __syncthreads();
    }
    #pragma unroll
    for (int rr = 0; rr < 8; rr++) {
        int r = rbase + ty * 8 + rr;
        if (r < M) {
            float4 v = make_float4(acc[rr][0], acc[rr][1], acc[rr][2], acc[rr][3]);
            *(float4*)(Out + (size_t)r * Ncol + cbase + tx * 4) = v;
        }
    }
}

// ---------------- per-(node,head) attention dots
__global__ void node_dots(const float* __restrict__ Hh, const float* __restrict__ a_s,
                          const float* __restrict__ a_d, float* __restrict__ ssrc,
                          float* __restrict__ sdst, int C, int Dfull) {
    int t = blockIdx.x * blockDim.x + threadIdx.x;
    if (t >= NNODES * HEADS) return;
    int n = t >> 2, h = t & 3;
    const float* hp = Hh + (size_t)n * Dfull + h * C;
    float s1 = 0.f, s2 = 0.f;
    for (int c = 0; c < C; c++) {
        float v = hp[c];
        s1 += v * a_s[h * C + c];
        s2 += v * a_d[h * C + c];
    }
    ssrc[t] = s1; sdst[t] = s2;
}

// ---------------- CSR build
__global__ void count_k(const int* __restrict__ ei, int* __restrict__ counts) {
    int t = blockIdx.x * blockDim.x + threadIdx.x;
    if (t >= ETOT) return;
    int d = (t < NEDGES) ? ei[NEDGES + t] : (t - NEDGES);
    atomicAdd(&counts[d], 1);
}

__global__ __launch_bounds__(1024) void scan_k(const int* __restrict__ counts, int* __restrict__ rowptr) {
    __shared__ int wsum[16];
    __shared__ int srun;
    const int t = threadIdx.x;
    const int lane = t & 63, wid = t >> 6;
    if (t == 0) srun = 0;
    __syncthreads();
    for (int base = 0; base < NNODES; base += 1024) {
        int idx = base + t;
        int v = (idx < NNODES) ? counts[idx] : 0;
        int x = v;
        #pragma unroll
        for (int off = 1; off < 64; off <<= 1) {
            int y = __shfl_up(x, off, 64);
            if (lane >= off) x += y;
        }
        if (lane == 63) wsum[wid] = x;
        __syncthreads();
        if (wid == 0) {
            int w = (lane < 16) ? wsum[lane] : 0;
            #pragma unroll
            for (int off = 1; off < 16; off <<= 1) {
                int y = __shfl_up(w, off, 64);
                if (lane >= off) w += y;
            }
            if (lane < 16) wsum[lane] = w;
        }
        __syncthreads();
        int wbase = (wid > 0) ? wsum[wid - 1] : 0;
        int run = srun;
        if (idx < NNODES) rowptr[idx] = run + wbase + x - v;
        __syncthreads();
        if (t == 1023) srun = run + wsum[15];
        __syncthreads();
    }
    if (t == 0) rowptr[NNODES] = srun;
}

__global__ void fill_k(const int* __restrict__ ei, const int* __restrict__ rowptr,
                       int* __restrict__ cursor, u16* __restrict__ esrc) {
    int t = blockIdx.x * blockDim.x + threadIdx.x;
    if (t >= ETOT) return;
    int s, d;
    if (t < NEDGES) { s = ei[t]; d = ei[NEDGES + t]; } else { s = t - NEDGES; d = s; }
    int pos = atomicAdd(&cursor[d], 1);
    esrc[rowptr[d] + pos] = (u16)s;
}

// ---------------- softmax stats + per-edge alpha (f16x4), wave per node, lanes over edges
__global__ __launch_bounds__(256) void gat_stats(const int* __restrict__ rowptr,
                                                 const u16* __restrict__ esrc,
                                                 const float* __restrict__ ssrc,
                                                 const float* __restrict__ sdst,
                                                 uint2* __restrict__ alpha) {
    int node = blockIdx.x * 4 + (threadIdx.x >> 6);
    if (node >= NNODES) return;
    int lane = threadIdx.x & 63;
    float4 sd = *(const float4*)(sdst + node * 4);
    int beg = rowptr[node], end = rowptr[node + 1];

    float m0 = -INFINITY, m1 = -INFINITY, m2 = -INFINITY, m3 = -INFINITY;
    for (int i = beg + lane; i < end; i += 64) {
        int s = esrc[i];
        float4 sp = *(const float4*)(ssrc + s * 4);
        m0 = fmaxf(m0, leaky(sp.x + sd.x));
        m1 = fmaxf(m1, leaky(sp.y + sd.y));
        m2 = fmaxf(m2, leaky(sp.z + sd.z));
        m3 = fmaxf(m3, leaky(sp.w + sd.w));
    }
    m0 = wave_max(m0); m1 = wave_max(m1); m2 = wave_max(m2); m3 = wave_max(m3);

    float d0 = 0.f, d1 = 0.f, d2 = 0.f, d3 = 0.f;
    for (int i = beg + lane; i < end; i += 64) {
        int s = esrc[i];
        float4 sp = *(const float4*)(ssrc + s * 4);
        d0 += expf(leaky(sp.x + sd.x) - m0);
        d1 += expf(leaky(sp.y + sd.y) - m1);
        d2 += expf(leaky(sp.z + sd.z) - m2);
        d3 += expf(leaky(sp.w + sd.w) - m3);
    }
    d0 = wave_sum(d0); d1 = wave_sum(d1); d2 = wave_sum(d2); d3 = wave_sum(d3);
    // denom >= 1 (max is attained), so +1e-16 is negligible: lsd = m + log(denom)
    float l0 = m0 + logf(d0), l1 = m1 + logf(d1);
    float l2 = m2 + logf(d2), l3 = m3 + logf(d3);

    for (int i = beg + lane; i < end; i += 64) {
        int s = esrc[i];
        float4 sp = *(const float4*)(ssrc + s * 4);
        float a0 = expf(leaky(sp.x + sd.x) - l0);
        float a1 = expf(leaky(sp.y + sd.y) - l1);
        float a2 = expf(leaky(sp.z + sd.z) - l2);
        float a3 = expf(leaky(sp.w + sd.w) - l3);
        uint2 pk;
        pk.x = ((unsigned)__half_as_ushort(__float2half_rn(a1)) << 16) | __half_as_ushort(__float2half_rn(a0));
        pk.y = ((unsigned)__half_as_ushort(__float2half_rn(a3)) << 16) | __half_as_ushort(__float2half_rn(a2));
        alpha[i] = pk;
    }
}

// ---------------- layer-1 accumulate: wave per node, lane = chans {lane, lane+64}
__global__ __launch_bounds__(256) void gat_acc1(const int* __restrict__ rowptr,
                                                const u16* __restrict__ esrc,
                                                const uint2* __restrict__ alpha,
                                                const float* __restrict__ BH,
                                                float* __restrict__ BO) {
    int node = blockIdx.x * 4 + (threadIdx.x >> 6);
    if (node >= NNODES) return;
    int lane = threadIdx.x & 63;
    bool hi = lane >= 32;               // chan0 head = lane>>5, chan1 head = 2+(lane>>5)
    int beg = rowptr[node], end = rowptr[node + 1];
    float acc0 = 0.f, acc1 = 0.f;
    int i = beg;
    for (; i + 2 <= end; i += 2) {
        int s0 = esrc[i], s1 = esrc[i + 1];
        uint2 p0 = alpha[i], p1 = alpha[i + 1];
        const float* h0 = BH + (size_t)s0 * D1;
        const float* h1 = BH + (size_t)s1 * D1;
        float b00 = h0[lane], b01 = h0[lane + 64];
        float b10 = h1[lane], b11 = h1[lane + 64];
        float2 f0lo = unpack_h2(p0.x), f0hi = unpack_h2(p0.y);
        float2 f1lo = unpack_h2(p1.x), f1hi = unpack_h2(p1.y);
        acc0 += (hi ? f0lo.y : f0lo.x) * b00 + (hi ? f1lo.y : f1lo.x) * b10;
        acc1 += (hi ? f0hi.y : f0hi.x) * b01 + (hi ? f1hi.y : f1hi.x) * b11;
    }
    if (i < end) {
        int s0 = esrc[i];
        uint2 p0 = alpha[i];
        const float* h0 = BH + (size_t)s0 * D1;
        float2 f0lo = unpack_h2(p0.x), f0hi = unpack_h2(p0.y);
        acc0 += (hi ? f0lo.y : f0lo.x) * h0[lane];
        acc1 += (hi ? f0hi.y : f0hi.x) * h0[lane + 64];
    }
    BO[(size_t)node * D1 + lane]      = acc0;
    BO[(size_t)node * D1 + lane + 64] = acc1;
}

// ---------------- layer-2 accumulate: wave per node, chans {lane, lane+64, lane+128(<32)}
__global__ __launch_bounds__(256) void gat_acc2(const int* __restrict__ rowptr,
                                                const u16* __restrict__ esrc,
                                                const uint2* __restrict__ alpha,
                                                const float* __restrict__ BH,
                                                float* __restrict__ BO) {
    int node = blockIdx.x * 4 + (threadIdx.x >> 6);
    if (node >= NNODES) return;
    int lane = threadIdx.x & 63;
    bool lo = lane < 40;        // chan0 head 0 else 1
    bool amid = lane < 16;      // chan1: head 1 / 2 / 3
    bool bmid = lane < 56;
    bool third = lane < 32;     // chan2 head 3
    int beg = rowptr[node], end = rowptr[node + 1];
    float acc0 = 0.f, acc1 = 0.f, acc2 = 0.f;
    int i = beg;
    for (; i + 2 <= end; i += 2) {
        int s0 = esrc[i], s1 = esrc[i + 1];
        uint2 p0 = alpha[i], p1 = alpha[i + 1];
        const float* h0 = BH + (size_t)s0 * D2;
        const float* h1 = BH + (size_t)s1 * D2;
        float b00 = h0[lane], b01 = h0[lane + 64], b02 = third ? h0[lane + 128] : 0.f;
        float b10 = h1[lane], b11 = h1[lane + 64], b12 = third ? h1[lane + 128] : 0.f;
        float2 f0lo = unpack_h2(p0.x), f0hi = unpack_h2(p0.y);
        float2 f1lo = unpack_h2(p1.x), f1hi = unpack_h2(p1.y);
        float aA0 = lo ? f0lo.x : f0lo.y, aA1 = lo ? f1lo.x : f1lo.y;
        float aB0 = amid ? f0lo.y : (bmid ? f0hi.x : f0hi.y);
        float aB1 = amid ? f1lo.y : (bmid ? f1hi.x : f1hi.y);
        acc0 += aA0 * b00 + aA1 * b10;
        acc1 += aB0 * b01 + aB1 * b11;
        acc2 += f0hi.y * b02 + f1hi.y * b12;
    }
    if (i < end) {
        int s0 = esrc[i];
        uint2 p0 = alpha[i];
        const float* h0 = BH + (size_t)s0 * D2;
        float2 f0lo = unpack_h2(p0.x), f0hi = unpack_h2(p0.y);
        float aA0 = lo ? f0lo.x : f0lo.y;
        float aB0 = amid ? f0lo.y : (bmid ? f0hi.x : f0hi.y);
        acc0 += aA0 * h0[lane];
        acc1 += aB0 * h0[lane + 64];
        if (third) acc2 += f0hi.y * h0[lane + 128];
    }
    BO[(size_t)node * D2 + lane]      = acc0;
    BO[(size_t)node * D2 + lane + 64] = acc1;
    if (third) BO[(size_t)node * D2 + lane + 128] = acc2;
}

// ---------------- bias + ELU + LayerNorm(128) in place, wave per node
__global__ __launch_bounds__(256) void elu_ln_k(float* __restrict__ BO, const float* __restrict__ b1,
                                                const float* __restrict__ g, const float* __restrict__ be) {
    int node = blockIdx.x * 4 + (threadIdx.x >> 6);
    if (node >= NNODES) return;
    int lane = threadIdx.x & 63;
    float* row = BO + (size_t)node * D1;
    float v0 = row[lane] + b1[lane];
    float v1 = row[lane + 64] + b1[lane + 64];
    v0 = v0 > 0.f ? v0 : expf(v0) - 1.f;
    v1 = v1 > 0.f ? v1 : expf(v1) - 1.f;
    float mu = wave_sum(v0 + v1) * (1.f / 128.f);
    float d0 = v0 - mu, d1 = v1 - mu;
    float var = wave_sum(d0 * d0 + d1 * d1) * (1.f / 128.f);
    float rs = rsqrtf(var + 1e-5f);
    row[lane] = d0 * rs * g[lane] + be[lane];
    row[lane + 64] = d1 * rs * g[lane + 64] + be[lane + 64];
}

// ---------------- head-mean + bias + LayerNorm(40) + log_softmax -> f32 out
__global__ __launch_bounds__(256) void final_k(const float* __restrict__ BO, const float* __restrict__ b2,
                                               const float* __restrict__ g, const float* __restrict__ be,
                                               float* __restrict__ out) {
    int node = blockIdx.x * 4 + (threadIdx.x >> 6);
    if (node >= NNODES) return;
    int lane = threadIdx.x & 63;
    bool act = lane < 40;
    int c = act ? lane : 0;
    const float* row = BO + (size_t)node * D2;
    float o = 0.f;
    if (act)
        o = 0.25f * (row[c] + row[40 + c] + row[80 + c] + row[120 + c]) + b2[c];
    float mu = wave_sum(act ? o : 0.f) * (1.f / 40.f);
    float dv = act ? o - mu : 0.f;
    float var = wave_sum(dv * dv) * (1.f / 40.f);
    float rs = rsqrtf(var + 1e-5f);
    float y = act ? dv * rs * g[c] + be[c] : -1e30f;
    float mx = wave_max(y);
    float ex = act ? expf(y - mx) : 0.f;
    float lse = logf(wave_sum(ex));
    if (act) out[(size_t)node * 40 + c] = y - mx - lse;
}

extern "C" void kernel_launch(void* const* d_in, const int* in_sizes, int n_in,
                              void* d_out, int out_size, void* d_ws, size_t ws_size,
                              hipStream_t stream) {
    const float* x   = (const float*)d_in[0];
    const int*   ei  = (const int*)d_in[1];
    const float* W1  = (const float*)d_in[2];
    const float* as1 = (const float*)d_in[3];
    const float* ad1 = (const float*)d_in[4];
    const float* b1  = (const float*)d_in[5];
    const float* W2  = (const float*)d_in[6];
    const float* as2 = (const float*)d_in[7];
    const float* ad2 = (const float*)d_in[8];
    const float* b2  = (const float*)d_in[9];
    const float* g0  = (const float*)d_in[10];
    const float* be0 = (const float*)d_in[11];
    const float* g1  = (const float*)d_in[12];
    const float* be1 = (const float*)d_in[13];

    float* ws = (float*)d_ws;
    float* BH   = ws;                           // 8,000,000
    float* BO   = ws + 8000000;                 // 8,000,000
    float* ssrc = ws + 16000000;                // 200,000
    float* sdst = ws + 16200000;                // 200,000
    uint2* alpha = (uint2*)(ws + 16400000);     // ETOT*8B = 1,700,000 f-units
    int*   rowptr = (int*)(ws + 18100000);      // 50,001
    u16*   esrc   = (u16*)(ws + 18150008);      // ETOT u16 = 425,000 f-units
    int*   counts = (int*)(ws + 18575008);      // 50,000
    int*   cursor = (int*)(ws + 18625008);      // 50,000  (ends 18,675,008 = 74.7 MB)

    const int eb = (ETOT + 255) / 256;
    const int nb4 = (NNODES + 3) / 4;

    // ---- CSR build (graph shared by both layers) ----
    hipMemsetAsync(counts, 0, NNODES * sizeof(int), stream);
    hipMemsetAsync(cursor, 0, NNODES * sizeof(int), stream);
    count_k<<<eb, 256, 0, stream>>>(ei, counts);
    scan_k<<<1, 1024, 0, stream>>>(counts, rowptr);
    fill_k<<<eb, 256, 0, stream>>>(ei, rowptr, cursor, esrc);

    // ================= layer 1 =================
    dim3 gg1((NNODES + 255) / 256, D1 / 32);
    gemm_tile<<<gg1, 256, 0, stream>>>(x, W1, BH, NNODES, FIN, D1);
    node_dots<<<(NNODES * 4 + 255) / 256, 256, 0, stream>>>(BH, as1, ad1, ssrc, sdst, C1, D1);
    gat_stats<<<nb4, 256, 0, stream>>>(rowptr, esrc, ssrc, sdst, alpha);
    gat_acc1<<<nb4, 256, 0, stream>>>(rowptr, esrc, alpha, BH, BO);
    elu_ln_k<<<nb4, 256, 0, stream>>>(BO, b1, g0, be0);

    // ================= layer 2 =================
    dim3 gg2((NNODES + 255) / 256, D2 / 32);
    gemm_tile<<<gg2, 256, 0, stream>>>(BO, W2, BH, NNODES, D1, D2);
    node_dots<<<(NNODES * 4 + 255) / 256, 256, 0, stream>>>(BH, as2, ad2, ssrc, sdst, C2, D2);
    gat_stats<<<nb4, 256, 0, stream>>>(rowptr, esrc, ssrc, sdst, alpha);
    gat_acc2<<<nb4, 256, 0, stream>>>(rowptr, esrc, alpha, BH, BO);
    final_k<<<nb4, 256, 0, stream>>>(BO, b2, g1, be1, (float*)d_out);
}

// Round 5
// 545.726 us; speedup vs baseline: 7.6193x; 1.2581x over previous
//
#include <hip/hip_runtime.h>
#include <hip/hip_bf16.h>
#include <hip/hip_fp16.h>

#define NNODES 50000
#define MPAD   50048          // NNODES rounded up to 64
#define NEDGES 800000
#define ETOT   (NEDGES + NNODES)
#define FIN    256
#define HEADS  4
#define C1     32
#define D1     128
#define C2     40
#define D2     160

typedef unsigned short u16;
typedef short v8s __attribute__((ext_vector_type(8)));
typedef float v4f __attribute__((ext_vector_type(4)));

__device__ __forceinline__ float bf2f(unsigned u) {
    union { unsigned u; float f; } x; x.u = u << 16; return x.f;
}
__device__ __forceinline__ u16 f2bf(float f) {
    unsigned u = __float_as_uint(f);
    return (u16)((u + 0x7fff + ((u >> 16) & 1)) >> 16);
}
__device__ __forceinline__ float wave_sum(float v) {
    #pragma unroll
    for (int m = 32; m > 0; m >>= 1) v += __shfl_xor(v, m, 64);
    return v;
}
__device__ __forceinline__ float wave_max(float v) {
    #pragma unroll
    for (int m = 32; m > 0; m >>= 1) v = fmaxf(v, __shfl_xor(v, m, 64));
    return v;
}
__device__ __forceinline__ float leaky(float x) { return fmaxf(x, 0.2f * x); }
__device__ __forceinline__ float2 unpack_h2(unsigned u) {
    union { unsigned u; __half2 h; } c; c.u = u;
    return __half22float2(c.h);
}

// ---------------- f32 -> bf16 convert with zero row padding (8 elems/thread)
__global__ void cvt_pad(const float* __restrict__ X, u16* __restrict__ Xb, int M, int Mpad, int K) {
    int i8 = (blockIdx.x * blockDim.x + threadIdx.x) * 8;
    if (i8 >= Mpad * K) return;
    int row = i8 / K;
    u16 o[8];
    if (row < M) {
        float4 a = *(const float4*)(X + i8);
        float4 b = *(const float4*)(X + i8 + 4);
        o[0]=f2bf(a.x); o[1]=f2bf(a.y); o[2]=f2bf(a.z); o[3]=f2bf(a.w);
        o[4]=f2bf(b.x); o[5]=f2bf(b.y); o[6]=f2bf(b.z); o[7]=f2bf(b.w);
    } else {
        #pragma unroll
        for (int j = 0; j < 8; j++) o[j] = 0;
    }
    *(uint4*)(Xb + i8) = *(uint4*)o;
}

// ---------------- repack W[K,N] (f32) into B-fragment order (bf16)
// Wf[((nt*KS + ks)*64 + lane)*8 + j] = W[ks*32 + (lane>>4)*8 + j][nt*16 + (lane&15)]
__global__ void repack_w(const float* __restrict__ W, u16* __restrict__ Wf, int K, int N, int total) {
    int idx = blockIdx.x * blockDim.x + threadIdx.x;
    if (idx >= total) return;
    int KS = K >> 5;
    int j = idx & 7, lane = (idx >> 3) & 63;
    int ks = (idx >> 9) % KS, nt = idx / (KS * 512);
    int k = ks * 32 + (lane >> 4) * 8 + j;
    int n = nt * 16 + (lane & 15);
    Wf[idx] = f2bf(W[(size_t)k * N + n]);
}

// ---------------- MFMA GEMM: Out[M, NT*16] = A[Mpad, KK] @ W, bf16 in, bf16 out
template <int KK, int NT>
__global__ __launch_bounds__(256) void gemm_mfma(const u16* __restrict__ A,
                                                 const u16* __restrict__ Wf,
                                                 u16* __restrict__ Out, int M) {
    const int KS = KK / 32;
    const int NCOL = NT * 16;
    int wid = threadIdx.x >> 6, lane = threadIdx.x & 63;
    int r0 = blockIdx.x * 64 + wid * 16;
    int m = lane & 15, quad = lane >> 4;

    v8s a[KS];
    const u16* ap = A + (size_t)(r0 + m) * KK + quad * 8;
    #pragma unroll
    for (int ks = 0; ks < KS; ks++) a[ks] = *(const v8s*)(ap + ks * 32);

    const v8s* bp0 = (const v8s*)Wf + lane;
    #pragma unroll 2
    for (int nt = 0; nt < NT; nt++) {
        v4f acc = {0.f, 0.f, 0.f, 0.f};
        const v8s* bp = bp0 + nt * KS * 64;
        #pragma unroll
        for (int ks = 0; ks < KS; ks++) {
            v8s b = bp[ks * 64];
            acc = __builtin_amdgcn_mfma_f32_16x16x32_bf16(a[ks], b, acc, 0, 0, 0);
        }
        int col = nt * 16 + m;
        #pragma unroll
        for (int reg = 0; reg < 4; reg++) {
            int r = r0 + quad * 4 + reg;
            if (r < M) Out[(size_t)r * NCOL + col] = f2bf(acc[reg]);
        }
    }
}

// ---------------- per-(node,head) attention dots, bf16 features
__global__ void node_dots_bf(const u16* __restrict__ Hh, const float* __restrict__ a_s,
                             const float* __restrict__ a_d, float* __restrict__ ssrc,
                             float* __restrict__ sdst, int C, int Dfull) {
    int t = blockIdx.x * blockDim.x + threadIdx.x;
    if (t >= NNODES * HEADS) return;
    int n = t >> 2, h = t & 3;
    const u16* hp = Hh + (size_t)n * Dfull + h * C;
    float s1 = 0.f, s2 = 0.f;
    for (int c = 0; c < C; c += 2) {
        unsigned v = *(const unsigned*)(hp + c);
        float v0 = bf2f(v & 0xffffu), v1 = bf2f(v >> 16);
        float2 as = *(const float2*)(a_s + h * C + c);
        float2 ad = *(const float2*)(a_d + h * C + c);
        s1 += v0 * as.x + v1 * as.y;
        s2 += v0 * ad.x + v1 * ad.y;
    }
    ssrc[t] = s1; sdst[t] = s2;
}

// ---------------- CSR build
__global__ void count_k(const int* __restrict__ ei, int* __restrict__ counts) {
    int t = blockIdx.x * blockDim.x + threadIdx.x;
    if (t >= ETOT) return;
    int d = (t < NEDGES) ? ei[NEDGES + t] : (t - NEDGES);
    atomicAdd(&counts[d], 1);
}

__global__ __launch_bounds__(1024) void scan_k(const int* __restrict__ counts, int* __restrict__ rowptr) {
    __shared__ int wsum[16];
    __shared__ int srun;
    const int t = threadIdx.x;
    const int lane = t & 63, wid = t >> 6;
    if (t == 0) srun = 0;
    __syncthreads();
    for (int base = 0; base < NNODES; base += 1024) {
        int idx = base + t;
        int v = (idx < NNODES) ? counts[idx] : 0;
        int x = v;
        #pragma unroll
        for (int off = 1; off < 64; off <<= 1) {
            int y = __shfl_up(x, off, 64);
            if (lane >= off) x += y;
        }
        if (lane == 63) wsum[wid] = x;
        __syncthreads();
        if (wid == 0) {
            int w = (lane < 16) ? wsum[lane] : 0;
            #pragma unroll
            for (int off = 1; off < 16; off <<= 1) {
                int y = __shfl_up(w, off, 64);
                if (lane >= off) w += y;
            }
            if (lane < 16) wsum[lane] = w;
        }
        __syncthreads();
        int wbase = (wid > 0) ? wsum[wid - 1] : 0;
        int run = srun;
        if (idx < NNODES) rowptr[idx] = run + wbase + x - v;
        __syncthreads();
        if (t == 1023) srun = run + wsum[15];
        __syncthreads();
    }
    if (t == 0) rowptr[NNODES] = srun;
}

__global__ void fill_k(const int* __restrict__ ei, const int* __restrict__ rowptr,
                       int* __restrict__ cursor, u16* __restrict__ esrc) {
    int t = blockIdx.x * blockDim.x + threadIdx.x;
    if (t >= ETOT) return;
    int s, d;
    if (t < NEDGES) { s = ei[t]; d = ei[NEDGES + t]; } else { s = t - NEDGES; d = s; }
    int pos = atomicAdd(&cursor[d], 1);
    esrc[rowptr[d] + pos] = (u16)s;
}

// ---------------- softmax stats + per-edge alpha (f16x4), lanes over edges
__global__ __launch_bounds__(256) void gat_stats(const int* __restrict__ rowptr,
                                                 const u16* __restrict__ esrc,
                                                 const float* __restrict__ ssrc,
                                                 const float* __restrict__ sdst,
                                                 uint2* __restrict__ alpha) {
    int node = blockIdx.x * 4 + (threadIdx.x >> 6);
    int lane = threadIdx.x & 63;
    float4 sd = *(const float4*)(sdst + node * 4);
    int beg = rowptr[node], end = rowptr[node + 1];

    float m0 = -INFINITY, m1 = -INFINITY, m2 = -INFINITY, m3 = -INFINITY;
    for (int i = beg + lane; i < end; i += 64) {
        int s = esrc[i];
        float4 sp = *(const float4*)(ssrc + s * 4);
        m0 = fmaxf(m0, leaky(sp.x + sd.x));
        m1 = fmaxf(m1, leaky(sp.y + sd.y));
        m2 = fmaxf(m2, leaky(sp.z + sd.z));
        m3 = fmaxf(m3, leaky(sp.w + sd.w));
    }
    m0 = wave_max(m0); m1 = wave_max(m1); m2 = wave_max(m2); m3 = wave_max(m3);

    float d0 = 0.f, d1 = 0.f, d2 = 0.f, d3 = 0.f;
    for (int i = beg + lane; i < end; i += 64) {
        int s = esrc[i];
        float4 sp = *(const float4*)(ssrc + s * 4);
        d0 += expf(leaky(sp.x + sd.x) - m0);
        d1 += expf(leaky(sp.y + sd.y) - m1);
        d2 += expf(leaky(sp.z + sd.z) - m2);
        d3 += expf(leaky(sp.w + sd.w) - m3);
    }
    d0 = wave_sum(d0); d1 = wave_sum(d1); d2 = wave_sum(d2); d3 = wave_sum(d3);
    float l0 = m0 + logf(d0), l1 = m1 + logf(d1);
    float l2 = m2 + logf(d2), l3 = m3 + logf(d3);

    for (int i = beg + lane; i < end; i += 64) {
        int s = esrc[i];
        float4 sp = *(const float4*)(ssrc + s * 4);
        float a0 = expf(leaky(sp.x + sd.x) - l0);
        float a1 = expf(leaky(sp.y + sd.y) - l1);
        float a2 = expf(leaky(sp.z + sd.z) - l2);
        float a3 = expf(leaky(sp.w + sd.w) - l3);
        uint2 pk;
        pk.x = ((unsigned)__half_as_ushort(__float2half_rn(a1)) << 16) | __half_as_ushort(__float2half_rn(a0));
        pk.y = ((unsigned)__half_as_ushort(__float2half_rn(a3)) << 16) | __half_as_ushort(__float2half_rn(a2));
        alpha[i] = pk;
    }
}

// ---------------- layer-1 accumulate + bias + ELU + LN, bf16 in/out
// lane holds channel pair {2*lane, 2*lane+1}; head = lane>>4
__global__ __launch_bounds__(256) void gat_acc1_ln(const int* __restrict__ rowptr,
                                                   const u16* __restrict__ esrc,
                                                   const uint2* __restrict__ alpha,
                                                   const u16* __restrict__ BH,
                                                   const float* __restrict__ b1,
                                                   const float* __restrict__ g,
                                                   const float* __restrict__ be,
                                                   u16* __restrict__ BOb) {
    int node = blockIdx.x * 4 + (threadIdx.x >> 6);
    int lane = threadIdx.x & 63;
    int head = lane >> 4;
    int beg = rowptr[node], end = rowptr[node + 1];
    float a0 = 0.f, a1 = 0.f;
    int i = beg;
    for (; i + 2 <= end; i += 2) {
        int s0 = esrc[i], s1 = esrc[i + 1];
        uint2 p0 = alpha[i], p1 = alpha[i + 1];
        unsigned h0 = *(const unsigned*)(BH + (size_t)s0 * D1 + 2 * lane);
        unsigned h1 = *(const unsigned*)(BH + (size_t)s1 * D1 + 2 * lane);
        float2 l0 = unpack_h2(p0.x), hi0 = unpack_h2(p0.y);
        float2 l1 = unpack_h2(p1.x), hi1 = unpack_h2(p1.y);
        float al0 = head == 0 ? l0.x : head == 1 ? l0.y : head == 2 ? hi0.x : hi0.y;
        float al1 = head == 0 ? l1.x : head == 1 ? l1.y : head == 2 ? hi1.x : hi1.y;
        a0 += al0 * bf2f(h0 & 0xffffu) + al1 * bf2f(h1 & 0xffffu);
        a1 += al0 * bf2f(h0 >> 16)     + al1 * bf2f(h1 >> 16);
    }
    if (i < end) {
        int s0 = esrc[i];
        uint2 p0 = alpha[i];
        unsigned h0 = *(const unsigned*)(BH + (size_t)s0 * D1 + 2 * lane);
        float2 l0 = unpack_h2(p0.x), hi0 = unpack_h2(p0.y);
        float al0 = head == 0 ? l0.x : head == 1 ? l0.y : head == 2 ? hi0.x : hi0.y;
        a0 += al0 * bf2f(h0 & 0xffffu);
        a1 += al0 * bf2f(h0 >> 16);
    }
    float2 bb = *(const float2*)(b1 + 2 * lane);
    float v0 = a0 + bb.x, v1 = a1 + bb.y;
    v0 = v0 > 0.f ? v0 : expf(v0) - 1.f;
    v1 = v1 > 0.f ? v1 : expf(v1) - 1.f;
    float mu = wave_sum(v0 + v1) * (1.f / 128.f);
    float d0 = v0 - mu, d1 = v1 - mu;
    float var = wave_sum(d0 * d0 + d1 * d1) * (1.f / 128.f);
    float rs = rsqrtf(var + 1e-5f);
    float2 gg = *(const float2*)(g + 2 * lane);
    float2 ee = *(const float2*)(be + 2 * lane);
    unsigned pk = ((unsigned)f2bf(d1 * rs * gg.y + ee.y) << 16) | f2bf(d0 * rs * gg.x + ee.x);
    *(unsigned*)(BOb + (size_t)node * D1 + 2 * lane) = pk;
}

// ---------------- layer-2 accumulate + head-mean + bias + LN + log_softmax -> f32 out
// lane: pair {2l,2l+1} head=lane/20; lanes<16 also pair {128+2l,129+2l} head 3
__global__ __launch_bounds__(256) void gat_acc2_fin(const int* __restrict__ rowptr,
                                                    const u16* __restrict__ esrc,
                                                    const uint2* __restrict__ alpha,
                                                    const u16* __restrict__ BH,
                                                    const float* __restrict__ b2,
                                                    const float* __restrict__ g,
                                                    const float* __restrict__ be,
                                                    float* __restrict__ out) {
    __shared__ float scr[4][160];
    int wid = threadIdx.x >> 6;
    int node = blockIdx.x * 4 + wid;
    int lane = threadIdx.x & 63;
    int head = lane / 20;
    bool third = lane < 16;
    int beg = rowptr[node], end = rowptr[node + 1];
    float a0 = 0.f, a1 = 0.f, a2 = 0.f, a3 = 0.f;
    for (int i = beg; i < end; i++) {
        int s = esrc[i];
        uint2 pk = alpha[i];
        float2 lo = unpack_h2(pk.x), hi = unpack_h2(pk.y);
        float alA = head == 0 ? lo.x : head == 1 ? lo.y : head == 2 ? hi.x : hi.y;
        unsigned h0 = *(const unsigned*)(BH + (size_t)s * D2 + 2 * lane);
        a0 += alA * bf2f(h0 & 0xffffu);
        a1 += alA * bf2f(h0 >> 16);
        if (third) {
            unsigned h1 = *(const unsigned*)(BH + (size_t)s * D2 + 128 + 2 * lane);
            a2 += hi.y * bf2f(h1 & 0xffffu);
            a3 += hi.y * bf2f(h1 >> 16);
        }
    }
    scr[wid][2 * lane] = a0;
    scr[wid][2 * lane + 1] = a1;
    if (third) { scr[wid][128 + 2 * lane] = a2; scr[wid][129 + 2 * lane] = a3; }
    __syncthreads();
    bool act = lane < 40;
    int c = act ? lane : 0;
    float o = 0.f;
    if (act)
        o = 0.25f * (scr[wid][c] + scr[wid][40 + c] + scr[wid][80 + c] + scr[wid][120 + c]) + b2[c];
    float mu = wave_sum(act ? o : 0.f) * (1.f / 40.f);
    float dv = act ? o - mu : 0.f;
    float var = wave_sum(dv * dv) * (1.f / 40.f);
    float rs = rsqrtf(var + 1e-5f);
    float y = act ? dv * rs * g[c] + be[c] : -1e30f;
    float mx = wave_max(y);
    float ex = act ? expf(y - mx) : 0.f;
    float lse = logf(wave_sum(ex));
    if (act) out[(size_t)node * 40 + c] = y - mx - lse;
}

extern "C" void kernel_launch(void* const* d_in, const int* in_sizes, int n_in,
                              void* d_out, int out_size, void* d_ws, size_t ws_size,
                              hipStream_t stream) {
    const float* x   = (const float*)d_in[0];
    const int*   ei  = (const int*)d_in[1];
    const float* W1  = (const float*)d_in[2];
    const float* as1 = (const float*)d_in[3];
    const float* ad1 = (const float*)d_in[4];
    const float* b1  = (const float*)d_in[5];
    const float* W2  = (const float*)d_in[6];
    const float* as2 = (const float*)d_in[7];
    const float* ad2 = (const float*)d_in[8];
    const float* b2  = (const float*)d_in[9];
    const float* g0  = (const float*)d_in[10];
    const float* be0 = (const float*)d_in[11];
    const float* g1  = (const float*)d_in[12];
    const float* be1 = (const float*)d_in[13];

    float* ws = (float*)d_ws;
    // layout in float units (61.9 MB total)
    u16*   xbf    = (u16*)ws;                       // MPAD*256 bf16 (also reused as BH2 in layer 2)
    u16*   BH2    = (u16*)ws;                       // 50000*160 bf16 (after gemm1 consumed xbf)
    u16*   BH1    = (u16*)(ws + 6406144);           // 50000*128 bf16
    u16*   BOb    = (u16*)(ws + 9606144);           // MPAD*128 bf16 (padded)
    float* ssrc   = ws + 12809216;                  // 200,000
    float* sdst   = ws + 13009216;                  // 200,000
    uint2* alpha  = (uint2*)(ws + 13209216);        // ETOT*8B
    int*   rowptr = (int*)(ws + 14909216);          // 50,001
    u16*   esrc   = (u16*)(ws + 14959220);          // ETOT u16
    int*   counts = (int*)(ws + 15384220);          // 50,000
    int*   cursor = (int*)(ws + 15434220);          // 50,000
    u16*   Wf1    = (u16*)(ws + 15484220);          // 32768 bf16
    u16*   Wf2    = (u16*)(ws + 15500604);          // 20480 bf16

    const int eb  = (ETOT + 255) / 256;
    const int nb4 = NNODES / 4;   // 12500, exact

    // ---- CSR build ----
    hipMemsetAsync(counts, 0, NNODES * sizeof(int), stream);
    hipMemsetAsync(cursor, 0, NNODES * sizeof(int), stream);
    count_k<<<eb, 256, 0, stream>>>(ei, counts);
    scan_k<<<1, 1024, 0, stream>>>(counts, rowptr);
    fill_k<<<eb, 256, 0, stream>>>(ei, rowptr, cursor, esrc);

    // ---- bf16 conversions / repacks ----
    cvt_pad<<<(MPAD * FIN / 8 + 255) / 256, 256, 0, stream>>>(x, xbf, NNODES, MPAD, FIN);
    repack_w<<<(8 * 8 * 512 + 255) / 256, 256, 0, stream>>>(W1, Wf1, FIN, D1, 8 * 8 * 512);
    repack_w<<<(10 * 4 * 512 + 255) / 256, 256, 0, stream>>>(W2, Wf2, D1, D2, 10 * 4 * 512);
    // zero pad rows of BOb (rows 50000..MPAD-1) for gemm2 A-frag reads
    hipMemsetAsync(BOb + (size_t)NNODES * D1, 0, (size_t)(MPAD - NNODES) * D1 * 2, stream);

    // ================= layer 1 =================
    gemm_mfma<FIN, 8><<<MPAD / 64, 256, 0, stream>>>(xbf, Wf1, BH1, NNODES);
    node_dots_bf<<<(NNODES * 4 + 255) / 256, 256, 0, stream>>>(BH1, as1, ad1, ssrc, sdst, C1, D1);
    gat_stats<<<nb4, 256, 0, stream>>>(rowptr, esrc, ssrc, sdst, alpha);
    gat_acc1_ln<<<nb4, 256, 0, stream>>>(rowptr, esrc, alpha, BH1, b1, g0, be0, BOb);

    // ================= layer 2 =================
    gemm_mfma<D1, 10><<<MPAD / 64, 256, 0, stream>>>(BOb, Wf2, BH2, NNODES);
    node_dots_bf<<<(NNODES * 4 + 255) / 256, 256, 0, stream>>>(BH2, as2, ad2, ssrc, sdst, C2, D2);
    gat_stats<<<nb4, 256, 0, stream>>>(rowptr, esrc, ssrc, sdst, alpha);
    gat_acc2_fin<<<nb4, 256, 0, stream>>>(rowptr, esrc, alpha, BH2, b2, g1, be1, (float*)d_out);
}

// Round 6
// 462.870 us; speedup vs baseline: 8.9832x; 1.1790x over previous
//
#include <hip/hip_runtime.h>
#include <hip/hip_bf16.h>
#include <hip/hip_fp16.h>

#define NNODES 50000
#define MPAD   50048          // NNODES rounded up to 64
#define NEDGES 800000
#define ETOT   (NEDGES + NNODES)
#define FIN    256
#define HEADS  4
#define C1     32
#define D1     128
#define C2     40
#define D2     160

typedef unsigned short u16;
typedef short v8s __attribute__((ext_vector_type(8)));
typedef float v4f __attribute__((ext_vector_type(4)));

__device__ __forceinline__ float bf2f(unsigned u) {
    union { unsigned u; float f; } x; x.u = u << 16; return x.f;
}
__device__ __forceinline__ u16 f2bf(float f) {
    unsigned u = __float_as_uint(f);
    return (u16)((u + 0x7fff + ((u >> 16) & 1)) >> 16);
}
__device__ __forceinline__ float wave_sum(float v) {
    #pragma unroll
    for (int m = 32; m > 0; m >>= 1) v += __shfl_xor(v, m, 64);
    return v;
}
__device__ __forceinline__ float wave_max(float v) {
    #pragma unroll
    for (int m = 32; m > 0; m >>= 1) v = fmaxf(v, __shfl_xor(v, m, 64));
    return v;
}
__device__ __forceinline__ float leaky(float x) { return fmaxf(x, 0.2f * x); }
__device__ __forceinline__ float2 unpack_h2(unsigned u) {
    union { unsigned u; __half2 h; } c; c.u = u;
    return __half22float2(c.h);
}

// ---------------- f32 -> bf16 convert with zero row padding (8 elems/thread)
__global__ void cvt_pad(const float* __restrict__ X, u16* __restrict__ Xb, int M, int Mpad, int K) {
    int i8 = (blockIdx.x * blockDim.x + threadIdx.x) * 8;
    if (i8 >= Mpad * K) return;
    int row = i8 / K;
    u16 o[8];
    if (row < M) {
        float4 a = *(const float4*)(X + i8);
        float4 b = *(const float4*)(X + i8 + 4);
        o[0]=f2bf(a.x); o[1]=f2bf(a.y); o[2]=f2bf(a.z); o[3]=f2bf(a.w);
        o[4]=f2bf(b.x); o[5]=f2bf(b.y); o[6]=f2bf(b.z); o[7]=f2bf(b.w);
    } else {
        #pragma unroll
        for (int j = 0; j < 8; j++) o[j] = 0;
    }
    *(uint4*)(Xb + i8) = *(uint4*)o;
}

// ---------------- repack W[K,N] (f32) into B-fragment order (bf16)
__global__ void repack_w(const float* __restrict__ W, u16* __restrict__ Wf, int K, int N, int total) {
    int idx = blockIdx.x * blockDim.x + threadIdx.x;
    if (idx >= total) return;
    int KS = K >> 5;
    int j = idx & 7, lane = (idx >> 3) & 63;
    int ks = (idx >> 9) % KS, nt = idx / (KS * 512);
    int k = ks * 32 + (lane >> 4) * 8 + j;
    int n = nt * 16 + (lane & 15);
    Wf[idx] = f2bf(W[(size_t)k * N + n]);
}

// ---------------- MFMA GEMM: Out[M, NT*16] = A[Mpad, KK] @ W, bf16 in, bf16 out
template <int KK, int NT>
__global__ __launch_bounds__(256) void gemm_mfma(const u16* __restrict__ A,
                                                 const u16* __restrict__ Wf,
                                                 u16* __restrict__ Out, int M) {
    const int KS = KK / 32;
    const int NCOL = NT * 16;
    int wid = threadIdx.x >> 6, lane = threadIdx.x & 63;
    int r0 = blockIdx.x * 64 + wid * 16;
    int m = lane & 15, quad = lane >> 4;

    v8s a[KS];
    const u16* ap = A + (size_t)(r0 + m) * KK + quad * 8;
    #pragma unroll
    for (int ks = 0; ks < KS; ks++) a[ks] = *(const v8s*)(ap + ks * 32);

    const v8s* bp0 = (const v8s*)Wf + lane;
    #pragma unroll 2
    for (int nt = 0; nt < NT; nt++) {
        v4f acc = {0.f, 0.f, 0.f, 0.f};
        const v8s* bp = bp0 + nt * KS * 64;
        #pragma unroll
        for (int ks = 0; ks < KS; ks++) {
            v8s b = bp[ks * 64];
            acc = __builtin_amdgcn_mfma_f32_16x16x32_bf16(a[ks], b, acc, 0, 0, 0);
        }
        int col = nt * 16 + m;
        #pragma unroll
        for (int reg = 0; reg < 4; reg++) {
            int r = r0 + quad * 4 + reg;
            if (r < M) Out[(size_t)r * NCOL + col] = f2bf(acc[reg]);
        }
    }
}

// ---------------- per-(node,head) attention dots, bf16 features
__global__ void node_dots_bf(const u16* __restrict__ Hh, const float* __restrict__ a_s,
                             const float* __restrict__ a_d, float* __restrict__ ssrc,
                             float* __restrict__ sdst, int C, int Dfull) {
    int t = blockIdx.x * blockDim.x + threadIdx.x;
    if (t >= NNODES * HEADS) return;
    int n = t >> 2, h = t & 3;
    const u16* hp = Hh + (size_t)n * Dfull + h * C;
    float s1 = 0.f, s2 = 0.f;
    for (int c = 0; c < C; c += 2) {
        unsigned v = *(const unsigned*)(hp + c);
        float v0 = bf2f(v & 0xffffu), v1 = bf2f(v >> 16);
        float2 as = *(const float2*)(a_s + h * C + c);
        float2 ad = *(const float2*)(a_d + h * C + c);
        s1 += v0 * as.x + v1 * as.y;
        s2 += v0 * ad.x + v1 * ad.y;
    }
    ssrc[t] = s1; sdst[t] = s2;
}

// ---------------- CSR build
__global__ void count_k(const int* __restrict__ ei, int* __restrict__ counts) {
    int t = blockIdx.x * blockDim.x + threadIdx.x;
    if (t >= ETOT) return;
    int d = (t < NEDGES) ? ei[NEDGES + t] : (t - NEDGES);
    atomicAdd(&counts[d], 1);
}

__global__ __launch_bounds__(1024) void scan_k(const int* __restrict__ counts, int* __restrict__ rowptr) {
    __shared__ int wsum[16];
    __shared__ int srun;
    const int t = threadIdx.x;
    const int lane = t & 63, wid = t >> 6;
    if (t == 0) srun = 0;
    __syncthreads();
    for (int base = 0; base < NNODES; base += 1024) {
        int idx = base + t;
        int v = (idx < NNODES) ? counts[idx] : 0;
        int x = v;
        #pragma unroll
        for (int off = 1; off < 64; off <<= 1) {
            int y = __shfl_up(x, off, 64);
            if (lane >= off) x += y;
        }
        if (lane == 63) wsum[wid] = x;
        __syncthreads();
        if (wid == 0) {
            int w = (lane < 16) ? wsum[lane] : 0;
            #pragma unroll
            for (int off = 1; off < 16; off <<= 1) {
                int y = __shfl_up(w, off, 64);
                if (lane >= off) w += y;
            }
            if (lane < 16) wsum[lane] = w;
        }
        __syncthreads();
        int wbase = (wid > 0) ? wsum[wid - 1] : 0;
        int run = srun;
        if (idx < NNODES) rowptr[idx] = run + wbase + x - v;
        __syncthreads();
        if (t == 1023) srun = run + wsum[15];
        __syncthreads();
    }
    if (t == 0) rowptr[NNODES] = srun;
}

__global__ void fill_k(const int* __restrict__ ei, const int* __restrict__ rowptr,
                       int* __restrict__ cursor, u16* __restrict__ esrc) {
    int t = blockIdx.x * blockDim.x + threadIdx.x;
    if (t >= ETOT) return;
    int s, d;
    if (t < NEDGES) { s = ei[t]; d = ei[NEDGES + t]; } else { s = t - NEDGES; d = s; }
    int pos = atomicAdd(&cursor[d], 1);
    esrc[rowptr[d] + pos] = (u16)s;
}

// ---------------- softmax stats + per-edge alpha (f16x4), lanes over edges
// fast path (deg<=64): single gather pass, e in registers, one exp + one divide
__global__ __launch_bounds__(256) void gat_stats(const int* __restrict__ rowptr,
                                                 const u16* __restrict__ esrc,
                                                 const float* __restrict__ ssrc,
                                                 const float* __restrict__ sdst,
                                                 uint2* __restrict__ alpha) {
    int node = blockIdx.x * 4 + (threadIdx.x >> 6);
    int lane = threadIdx.x & 63;
    float4 sd = *(const float4*)(sdst + node * 4);
    int beg = rowptr[node], end = rowptr[node + 1];
    int deg = end - beg;

    if (deg <= 64) {
        bool on = lane < deg;
        int idx = beg + (on ? lane : 0);
        int s = esrc[idx];
        float4 sp = *(const float4*)(ssrc + s * 4);
        float e0 = on ? leaky(sp.x + sd.x) : -INFINITY;
        float e1 = on ? leaky(sp.y + sd.y) : -INFINITY;
        float e2 = on ? leaky(sp.z + sd.z) : -INFINITY;
        float e3 = on ? leaky(sp.w + sd.w) : -INFINITY;
        float m0 = wave_max(e0), m1 = wave_max(e1);
        float m2 = wave_max(e2), m3 = wave_max(e3);
        float p0 = expf(e0 - m0), p1 = expf(e1 - m1);   // off lanes -> exp(-inf)=0
        float p2 = expf(e2 - m2), p3 = expf(e3 - m3);
        float r0 = 1.f / wave_sum(p0), r1 = 1.f / wave_sum(p1);
        float r2 = 1.f / wave_sum(p2), r3 = 1.f / wave_sum(p3);
        if (on) {
            uint2 pk;
            pk.x = ((unsigned)__half_as_ushort(__float2half_rn(p1 * r1)) << 16) | __half_as_ushort(__float2half_rn(p0 * r0));
            pk.y = ((unsigned)__half_as_ushort(__float2half_rn(p3 * r3)) << 16) | __half_as_ushort(__float2half_rn(p2 * r2));
            alpha[idx] = pk;
        }
        return;
    }

    // fallback: 3-pass (rare, deg > 64)
    float m0 = -INFINITY, m1 = -INFINITY, m2 = -INFINITY, m3 = -INFINITY;
    for (int i = beg + lane; i < end; i += 64) {
        int s = esrc[i];
        float4 sp = *(const float4*)(ssrc + s * 4);
        m0 = fmaxf(m0, leaky(sp.x + sd.x));
        m1 = fmaxf(m1, leaky(sp.y + sd.y));
        m2 = fmaxf(m2, leaky(sp.z + sd.z));
        m3 = fmaxf(m3, leaky(sp.w + sd.w));
    }
    m0 = wave_max(m0); m1 = wave_max(m1); m2 = wave_max(m2); m3 = wave_max(m3);
    float d0 = 0.f, d1 = 0.f, d2 = 0.f, d3 = 0.f;
    for (int i = beg + lane; i < end; i += 64) {
        int s = esrc[i];
        float4 sp = *(const float4*)(ssrc + s * 4);
        d0 += expf(leaky(sp.x + sd.x) - m0);
        d1 += expf(leaky(sp.y + sd.y) - m1);
        d2 += expf(leaky(sp.z + sd.z) - m2);
        d3 += expf(leaky(sp.w + sd.w) - m3);
    }
    d0 = wave_sum(d0); d1 = wave_sum(d1); d2 = wave_sum(d2); d3 = wave_sum(d3);
    float l0 = m0 + logf(d0), l1 = m1 + logf(d1);
    float l2 = m2 + logf(d2), l3 = m3 + logf(d3);
    for (int i = beg + lane; i < end; i += 64) {
        int s = esrc[i];
        float4 sp = *(const float4*)(ssrc + s * 4);
        float a0 = expf(leaky(sp.x + sd.x) - l0);
        float a1 = expf(leaky(sp.y + sd.y) - l1);
        float a2 = expf(leaky(sp.z + sd.z) - l2);
        float a3 = expf(leaky(sp.w + sd.w) - l3);
        uint2 pk;
        pk.x = ((unsigned)__half_as_ushort(__float2half_rn(a1)) << 16) | __half_as_ushort(__float2half_rn(a0));
        pk.y = ((unsigned)__half_as_ushort(__float2half_rn(a3)) << 16) | __half_as_ushort(__float2half_rn(a2));
        alpha[i] = pk;
    }
}

// ---------------- layer-1 accumulate + bias + ELU + LN, bf16 in/out
// lane cl=lane&31 holds chans {4cl..4cl+3}; lanes 32..63 duplicate (reductions /256)
__global__ __launch_bounds__(256) void gat_acc1_ln(const int* __restrict__ rowptr,
                                                   const u16* __restrict__ esrc,
                                                   const uint2* __restrict__ alpha,
                                                   const u16* __restrict__ BH,
                                                   const float* __restrict__ b1,
                                                   const float* __restrict__ g,
                                                   const float* __restrict__ be,
                                                   u16* __restrict__ BOb) {
    __shared__ int   s_src[4][64];
    __shared__ uint2 s_al[4][64];
    int wid = threadIdx.x >> 6;
    int node = blockIdx.x * 4 + wid;
    int lane = threadIdx.x & 63;
    int cl = lane & 31;
    int head = cl >> 3;
    int beg = rowptr[node], end = rowptr[node + 1];
    float a0 = 0.f, a1 = 0.f, a2 = 0.f, a3 = 0.f;
    for (int tb = beg; tb < end; tb += 64) {
        int nj = end - tb; if (nj > 64) nj = 64;
        if (lane < nj) {
            s_src[wid][lane] = esrc[tb + lane];
            s_al[wid][lane]  = alpha[tb + lane];
        }
        #pragma unroll 4
        for (int j = 0; j < nj; j++) {
            int s = s_src[wid][j];
            uint2 pk = s_al[wid][j];
            float2 lo = unpack_h2(pk.x), hi = unpack_h2(pk.y);
            float al = head == 0 ? lo.x : head == 1 ? lo.y : head == 2 ? hi.x : hi.y;
            uint2 h = *(const uint2*)(BH + (size_t)s * D1 + 4 * cl);
            a0 += al * bf2f(h.x & 0xffffu);
            a1 += al * bf2f(h.x >> 16);
            a2 += al * bf2f(h.y & 0xffffu);
            a3 += al * bf2f(h.y >> 16);
        }
    }
    float4 bb = *(const float4*)(b1 + 4 * cl);
    float v0 = a0 + bb.x, v1 = a1 + bb.y, v2 = a2 + bb.z, v3 = a3 + bb.w;
    v0 = v0 > 0.f ? v0 : expf(v0) - 1.f;
    v1 = v1 > 0.f ? v1 : expf(v1) - 1.f;
    v2 = v2 > 0.f ? v2 : expf(v2) - 1.f;
    v3 = v3 > 0.f ? v3 : expf(v3) - 1.f;
    float mu = wave_sum(v0 + v1 + v2 + v3) * (1.f / 256.f);   // channels counted twice
    float d0 = v0 - mu, d1 = v1 - mu, d2 = v2 - mu, d3 = v3 - mu;
    float var = wave_sum(d0 * d0 + d1 * d1 + d2 * d2 + d3 * d3) * (1.f / 256.f);
    float rs = rsqrtf(var + 1e-5f);
    if (lane < 32) {
        float4 gg = *(const float4*)(g + 4 * cl);
        float4 ee = *(const float4*)(be + 4 * cl);
        uint2 pk;
        pk.x = ((unsigned)f2bf(d1 * rs * gg.y + ee.y) << 16) | f2bf(d0 * rs * gg.x + ee.x);
        pk.y = ((unsigned)f2bf(d3 * rs * gg.w + ee.w) << 16) | f2bf(d2 * rs * gg.z + ee.z);
        *(uint2*)(BOb + (size_t)node * D1 + 4 * cl) = pk;
    }
}

// ---------------- layer-2 accumulate + head-mean + bias + LN + log_softmax -> f32 out
// lane cl = (lane<40 ? lane : lane-40) holds chans {4cl..4cl+3}; head = cl/10
__global__ __launch_bounds__(256) void gat_acc2_fin(const int* __restrict__ rowptr,
                                                    const u16* __restrict__ esrc,
                                                    const uint2* __restrict__ alpha,
                                                    const u16* __restrict__ BH,
                                                    const float* __restrict__ b2,
                                                    const float* __restrict__ g,
                                                    const float* __restrict__ be,
                                                    float* __restrict__ out) {
    __shared__ int   s_src[4][64];
    __shared__ uint2 s_al[4][64];
    __shared__ float scr[4][160];
    int wid = threadIdx.x >> 6;
    int node = blockIdx.x * 4 + wid;
    int lane = threadIdx.x & 63;
    int cl = lane < 40 ? lane : lane - 40;
    int head = cl / 10;
    int beg = rowptr[node], end = rowptr[node + 1];
    float a0 = 0.f, a1 = 0.f, a2 = 0.f, a3 = 0.f;
    for (int tb = beg; tb < end; tb += 64) {
        int nj = end - tb; if (nj > 64) nj = 64;
        if (lane < nj) {
            s_src[wid][lane] = esrc[tb + lane];
            s_al[wid][lane]  = alpha[tb + lane];
        }
        #pragma unroll 4
        for (int j = 0; j < nj; j++) {
            int s = s_src[wid][j];
            uint2 pk = s_al[wid][j];
            float2 lo = unpack_h2(pk.x), hi = unpack_h2(pk.y);
            float al = head == 0 ? lo.x : head == 1 ? lo.y : head == 2 ? hi.x : hi.y;
            uint2 h = *(const uint2*)(BH + (size_t)s * D2 + 4 * cl);
            a0 += al * bf2f(h.x & 0xffffu);
            a1 += al * bf2f(h.x >> 16);
            a2 += al * bf2f(h.y & 0xffffu);
            a3 += al * bf2f(h.y >> 16);
        }
    }
    if (lane < 40)
        *(float4*)&scr[wid][4 * cl] = make_float4(a0, a1, a2, a3);
    // wave-private LDS: no block barrier needed
    bool act = lane < 40;
    int c = act ? lane : 0;
    float o = 0.f;
    if (act)
        o = 0.25f * (scr[wid][c] + scr[wid][40 + c] + scr[wid][80 + c] + scr[wid][120 + c]) + b2[c];
    float mu = wave_sum(act ? o : 0.f) * (1.f / 40.f);
    float dv = act ? o - mu : 0.f;
    float var = wave_sum(dv * dv) * (1.f / 40.f);
    float rs = rsqrtf(var + 1e-5f);
    float y = act ? dv * rs * g[c] + be[c] : -1e30f;
    float mx = wave_max(y);
    float ex = act ? expf(y - mx) : 0.f;
    float lse = logf(wave_sum(ex));
    if (act) out[(size_t)node * 40 + c] = y - mx - lse;
}

extern "C" void kernel_launch(void* const* d_in, const int* in_sizes, int n_in,
                              void* d_out, int out_size, void* d_ws, size_t ws_size,
                              hipStream_t stream) {
    const float* x   = (const float*)d_in[0];
    const int*   ei  = (const int*)d_in[1];
    const float* W1  = (const float*)d_in[2];
    const float* as1 = (const float*)d_in[3];
    const float* ad1 = (const float*)d_in[4];
    const float* b1  = (const float*)d_in[5];
    const float* W2  = (const float*)d_in[6];
    const float* as2 = (const float*)d_in[7];
    const float* ad2 = (const float*)d_in[8];
    const float* b2  = (const float*)d_in[9];
    const float* g0  = (const float*)d_in[10];
    const float* be0 = (const float*)d_in[11];
    const float* g1  = (const float*)d_in[12];
    const float* be1 = (const float*)d_in[13];

    float* ws = (float*)d_ws;
    u16*   xbf    = (u16*)ws;                       // MPAD*256 bf16 (reused as BH2)
    u16*   BH2    = (u16*)ws;
    u16*   BH1    = (u16*)(ws + 6406144);           // 50000*128 bf16
    u16*   BOb    = (u16*)(ws + 9606144);           // MPAD*128 bf16 (padded)
    float* ssrc   = ws + 12809216;
    float* sdst   = ws + 13009216;
    uint2* alpha  = (uint2*)(ws + 13209216);        // ETOT*8B
    int*   rowptr = (int*)(ws + 14909216);
    u16*   esrc   = (u16*)(ws + 14959220);
    int*   counts = (int*)(ws + 15384220);
    int*   cursor = (int*)(ws + 15434220);
    u16*   Wf1    = (u16*)(ws + 15484220);
    u16*   Wf2    = (u16*)(ws + 15500604);

    const int eb  = (ETOT + 255) / 256;
    const int nb4 = NNODES / 4;

    // ---- CSR build ----
    hipMemsetAsync(counts, 0, NNODES * sizeof(int), stream);
    hipMemsetAsync(cursor, 0, NNODES * sizeof(int), stream);
    count_k<<<eb, 256, 0, stream>>>(ei, counts);
    scan_k<<<1, 1024, 0, stream>>>(counts, rowptr);
    fill_k<<<eb, 256, 0, stream>>>(ei, rowptr, cursor, esrc);

    // ---- bf16 conversions / repacks ----
    cvt_pad<<<(MPAD * FIN / 8 + 255) / 256, 256, 0, stream>>>(x, xbf, NNODES, MPAD, FIN);
    repack_w<<<(8 * 8 * 512 + 255) / 256, 256, 0, stream>>>(W1, Wf1, FIN, D1, 8 * 8 * 512);
    repack_w<<<(10 * 4 * 512 + 255) / 256, 256, 0, stream>>>(W2, Wf2, D1, D2, 10 * 4 * 512);
    hipMemsetAsync(BOb + (size_t)NNODES * D1, 0, (size_t)(MPAD - NNODES) * D1 * 2, stream);

    // ================= layer 1 =================
    gemm_mfma<FIN, 8><<<MPAD / 64, 256, 0, stream>>>(xbf, Wf1, BH1, NNODES);
    node_dots_bf<<<(NNODES * 4 + 255) / 256, 256, 0, stream>>>(BH1, as1, ad1, ssrc, sdst, C1, D1);
    gat_stats<<<nb4, 256, 0, stream>>>(rowptr, esrc, ssrc, sdst, alpha);
    gat_acc1_ln<<<nb4, 256, 0, stream>>>(rowptr, esrc, alpha, BH1, b1, g0, be0, BOb);

    // ================= layer 2 =================
    gemm_mfma<D1, 10><<<MPAD / 64, 256, 0, stream>>>(BOb, Wf2, BH2, NNODES);
    node_dots_bf<<<(NNODES * 4 + 255) / 256, 256, 0, stream>>>(BH2, as2, ad2, ssrc, sdst, C2, D2);
    gat_stats<<<nb4, 256, 0, stream>>>(rowptr, esrc, ssrc, sdst, alpha);
    gat_acc2_fin<<<nb4, 256, 0, stream>>>(rowptr, esrc, alpha, BH2, b2, g1, be1, (float*)d_out);
}

// Round 8
// 362.309 us; speedup vs baseline: 11.4765x; 1.2776x over previous
//
#include <hip/hip_runtime.h>
#include <hip/hip_bf16.h>
#include <hip/hip_fp16.h>

#define NNODES 50000
#define MPAD   50048
#define NEDGES 800000
#define ETOT   (NEDGES + NNODES)
#define FIN    256
#define HEADS  4
#define C1     32
#define D1     128
#define C2     40
#define D2     160

typedef unsigned short u16;
typedef short v8s __attribute__((ext_vector_type(8)));
typedef float v4f __attribute__((ext_vector_type(4)));

__device__ __forceinline__ float bf2f(unsigned u) {
    union { unsigned u; float f; } x; x.u = u << 16; return x.f;
}
__device__ __forceinline__ u16 f2bf(float f) {
    unsigned u = __float_as_uint(f);
    return (u16)((u + 0x7fff + ((u >> 16) & 1)) >> 16);
}
__device__ __forceinline__ float wave_sum(float v) {
    #pragma unroll
    for (int m = 32; m > 0; m >>= 1) v += __shfl_xor(v, m, 64);
    return v;
}
__device__ __forceinline__ float wave_max(float v) {
    #pragma unroll
    for (int m = 32; m > 0; m >>= 1) v = fmaxf(v, __shfl_xor(v, m, 64));
    return v;
}
__device__ __forceinline__ float leaky(float x) { return fmaxf(x, 0.2f * x); }
__device__ __forceinline__ float2 unpack_h2(unsigned u) {
    union { unsigned u; __half2 h; } c; c.u = u;
    return __half22float2(c.h);
}
__device__ __forceinline__ unsigned pack_h2(float a, float b) {
    return ((unsigned)__half_as_ushort(__float2half_rn(b)) << 16) | __half_as_ushort(__float2half_rn(a));
}

// ---------------- repack W[K,N] f32 -> MFMA B-fragment order bf16, plus one
// extra 16-col tile: col h = W @ a_src_h (zero-extended), col 4+h = W @ a_dst_h
__global__ void repack_all(const float* __restrict__ W, const float* __restrict__ as,
                           const float* __restrict__ ad, u16* __restrict__ Wf,
                           int K, int N, int C, int total) {
    int idx = blockIdx.x * blockDim.x + threadIdx.x;
    if (idx >= total) return;
    int KS = K >> 5, NT = N >> 4;
    int j = idx & 7, lane = (idx >> 3) & 63;
    int rest = idx >> 9;
    int ks = rest % KS, nt = rest / KS;
    int k = ks * 32 + (lane >> 4) * 8 + j;
    int n16 = lane & 15;
    float val = 0.f;
    if (nt < NT) {
        val = W[(size_t)k * N + nt * 16 + n16];
    } else if (n16 < 8) {
        int h = n16 & 3;
        const float* av = (n16 < 4) ? as : ad;
        float s = 0.f;
        for (int c = 0; c < C; c++) s += W[(size_t)k * N + h * C + c] * av[h * C + c];
        val = s;
    }
    Wf[idx] = f2bf(val);
}

// ---------------- MFMA GEMM + fused attention dots
// Out[M, NT*16] bf16 = A[M,KK] @ W; ext tile -> ssrc/sdst[M*4]
template <bool AF32, int KK, int NT>
__global__ __launch_bounds__(256) void gemm_mfma(const void* __restrict__ Aptr,
                                                 const u16* __restrict__ Wf,
                                                 u16* __restrict__ Out,
                                                 float* __restrict__ ssrc,
                                                 float* __restrict__ sdst, int M) {
    const int KS = KK / 32;
    const int NCOL = NT * 16;
    int wid = threadIdx.x >> 6, lane = threadIdx.x & 63;
    int r0 = blockIdx.x * 64 + wid * 16;
    int m = lane & 15, quad = lane >> 4;
    int row = r0 + m;
    bool rowok = row < M;

    v8s a[KS];
    if (AF32) {
        const float* ap = (const float*)Aptr + (size_t)(rowok ? row : 0) * KK + quad * 8;
        #pragma unroll
        for (int ks = 0; ks < KS; ks++) {
            if (rowok) {
                float4 fa = *(const float4*)(ap + ks * 32);
                float4 fb = *(const float4*)(ap + ks * 32 + 4);
                u16 t[8] = {f2bf(fa.x), f2bf(fa.y), f2bf(fa.z), f2bf(fa.w),
                            f2bf(fb.x), f2bf(fb.y), f2bf(fb.z), f2bf(fb.w)};
                a[ks] = *(v8s*)t;
            } else {
                a[ks] = (v8s){0,0,0,0,0,0,0,0};
            }
        }
    } else {
        const u16* ap = (const u16*)Aptr + (size_t)(rowok ? row : 0) * KK + quad * 8;
        #pragma unroll
        for (int ks = 0; ks < KS; ks++)
            a[ks] = rowok ? *(const v8s*)(ap + ks * 32) : (v8s){0,0,0,0,0,0,0,0};
    }

    const v8s* bp0 = (const v8s*)Wf + lane;
    #pragma unroll 2
    for (int nt = 0; nt < NT; nt++) {
        v4f acc = {0.f, 0.f, 0.f, 0.f};
        const v8s* bp = bp0 + nt * KS * 64;
        #pragma unroll
        for (int ks = 0; ks < KS; ks++)
            acc = __builtin_amdgcn_mfma_f32_16x16x32_bf16(a[ks], bp[ks * 64], acc, 0, 0, 0);
        int col = nt * 16 + m;
        #pragma unroll
        for (int reg = 0; reg < 4; reg++) {
            int r = r0 + quad * 4 + reg;
            if (r < M) Out[(size_t)r * NCOL + col] = f2bf(acc[reg]);
        }
    }
    // ext tile: attention dots
    {
        v4f acc = {0.f, 0.f, 0.f, 0.f};
        const v8s* bp = bp0 + NT * KS * 64;
        #pragma unroll
        for (int ks = 0; ks < KS; ks++)
            acc = __builtin_amdgcn_mfma_f32_16x16x32_bf16(a[ks], bp[ks * 64], acc, 0, 0, 0);
        if (m < 8) {
            float* tgt = (m < 4) ? ssrc : sdst;
            int h = m & 3;
            #pragma unroll
            for (int reg = 0; reg < 4; reg++) {
                int r = r0 + quad * 4 + reg;
                if (r < M) tgt[r * 4 + h] = acc[reg];
            }
        }
    }
}

// ---------------- CSR build
__global__ void count_k(const int* __restrict__ ei, int* __restrict__ counts) {
    int t = blockIdx.x * blockDim.x + threadIdx.x;
    if (t >= ETOT) return;
    int d = (t < NEDGES) ? ei[NEDGES + t] : (t - NEDGES);
    atomicAdd(&counts[d], 1);
}

__global__ __launch_bounds__(1024) void scan_k(const int* __restrict__ counts, int* __restrict__ rowptr) {
    __shared__ int wsum[16];
    __shared__ int srun;
    const int t = threadIdx.x;
    const int lane = t & 63, wid = t >> 6;
    if (t == 0) srun = 0;
    __syncthreads();
    for (int base = 0; base < NNODES; base += 4096) {
        int i4 = base + t * 4;
        int4 v = make_int4(0, 0, 0, 0);
        if (i4 < NNODES) v = *(const int4*)(counts + i4);
        int tsum = v.x + v.y + v.z + v.w;
        int x = tsum;
        #pragma unroll
        for (int off = 1; off < 64; off <<= 1) {
            int y = __shfl_up(x, off, 64);
            if (lane >= off) x += y;
        }
        if (lane == 63) wsum[wid] = x;
        __syncthreads();
        if (wid == 0) {
            int w = (lane < 16) ? wsum[lane] : 0;
            #pragma unroll
            for (int off = 1; off < 16; off <<= 1) {
                int y = __shfl_up(w, off, 64);
                if (lane >= off) w += y;
            }
            if (lane < 16) wsum[lane] = w;
        }
        __syncthreads();
        int wbase = (wid > 0) ? wsum[wid - 1] : 0;
        int run = srun;
        int pre = run + wbase + x - tsum;
        if (i4 < NNODES) {
            rowptr[i4]     = pre;
            rowptr[i4 + 1] = pre + v.x;
            rowptr[i4 + 2] = pre + v.x + v.y;
            rowptr[i4 + 3] = pre + v.x + v.y + v.z;
        }
        __syncthreads();
        if (t == 1023) srun = run + wsum[15];
        __syncthreads();
    }
    if (t == 0) rowptr[NNODES] = srun;
}

__global__ void fill_k(const int* __restrict__ ei, const int* __restrict__ rowptr,
                       int* __restrict__ cursor, u16* __restrict__ esrc) {
    int t = blockIdx.x * blockDim.x + threadIdx.x;
    if (t >= ETOT) return;
    int s, d;
    if (t < NEDGES) { s = ei[t]; d = ei[NEDGES + t]; } else { s = t - NEDGES; d = s; }
    int pos = atomicAdd(&cursor[d], 1);
    esrc[rowptr[d] + pos] = (u16)s;
}

// phase A shared by both fused kernels: tile softmax update.
#define PHASE_A(SRC_ARR, AL_ARR)                                                   \
    int nj = end - tb; if (nj > 64) nj = 64;                                       \
    bool on = lane < nj;                                                           \
    int sE = 0;                                                                    \
    if (on) { sE = esrc[tb + lane]; SRC_ARR[wid][lane] = sE; }                     \
    float4 sp = *(const float4*)(ssrc + sE * 4);                                   \
    float e0 = on ? leaky(sp.x + sd.x) : -INFINITY;                                \
    float e1 = on ? leaky(sp.y + sd.y) : -INFINITY;                                \
    float e2 = on ? leaky(sp.z + sd.z) : -INFINITY;                                \
    float e3 = on ? leaky(sp.w + sd.w) : -INFINITY;                                \
    float nm0 = fmaxf(m0, wave_max(e0)), nm1 = fmaxf(m1, wave_max(e1));            \
    float nm2 = fmaxf(m2, wave_max(e2)), nm3 = fmaxf(m3, wave_max(e3));            \
    float sc0 = expf(m0 - nm0), sc1 = expf(m1 - nm1);                              \
    float sc2 = expf(m2 - nm2), sc3 = expf(m3 - nm3);                              \
    float p0 = expf(e0 - nm0), p1 = expf(e1 - nm1);                                \
    float p2 = expf(e2 - nm2), p3 = expf(e3 - nm3);                                \
    den0 = den0 * sc0 + wave_sum(p0); den1 = den1 * sc1 + wave_sum(p1);            \
    den2 = den2 * sc2 + wave_sum(p2); den3 = den3 * sc3 + wave_sum(p3);            \
    m0 = nm0; m1 = nm1; m2 = nm2; m3 = nm3;                                        \
    if (on) { uint2 pk; pk.x = pack_h2(p0, p1); pk.y = pack_h2(p2, p3);            \
              AL_ARR[wid][lane] = pk; }

// ---------------- layer 1: gather + softmax + bias + ELU + LN -> bf16 BOb
__global__ __launch_bounds__(256) void gat_fused1(const int* __restrict__ rowptr,
                                                  const u16* __restrict__ esrc,
                                                  const float* __restrict__ ssrc,
                                                  const float* __restrict__ sdst,
                                                  const u16* __restrict__ BH,
                                                  const float* __restrict__ b1,
                                                  const float* __restrict__ g,
                                                  const float* __restrict__ be,
                                                  u16* __restrict__ BOb) {
    __shared__ int   s_src[4][64];
    __shared__ uint2 s_al[4][64];
    int wid = threadIdx.x >> 6, lane = threadIdx.x & 63;
    int node = blockIdx.x * 4 + wid;
    int l8 = lane & 15, grp = lane >> 4;
    int head = l8 >> 2;
    float4 sd = *(const float4*)(sdst + node * 4);
    int beg = rowptr[node], end = rowptr[node + 1];
    float m0 = -INFINITY, m1 = -INFINITY, m2 = -INFINITY, m3 = -INFINITY;
    float den0 = 0.f, den1 = 0.f, den2 = 0.f, den3 = 0.f;
    float acc[8];
    #pragma unroll
    for (int i = 0; i < 8; i++) acc[i] = 0.f;

    for (int tb = beg; tb < end; tb += 64) {
        PHASE_A(s_src, s_al)
        float scl = head == 0 ? sc0 : head == 1 ? sc1 : head == 2 ? sc2 : sc3;
        #pragma unroll
        for (int i = 0; i < 8; i++) acc[i] *= scl;
        #pragma unroll 2
        for (int j = grp; j < nj; j += 4) {
            int sj = s_src[wid][j];
            uint2 pk = s_al[wid][j];
            float2 lof = unpack_h2(pk.x), hif = unpack_h2(pk.y);
            float al = head == 0 ? lof.x : head == 1 ? lof.y : head == 2 ? hif.x : hif.y;
            uint4 h = *(const uint4*)(BH + (size_t)sj * D1 + l8 * 8);
            acc[0] += al * bf2f(h.x & 0xffffu); acc[1] += al * bf2f(h.x >> 16);
            acc[2] += al * bf2f(h.y & 0xffffu); acc[3] += al * bf2f(h.y >> 16);
            acc[4] += al * bf2f(h.z & 0xffffu); acc[5] += al * bf2f(h.z >> 16);
            acc[6] += al * bf2f(h.w & 0xffffu); acc[7] += al * bf2f(h.w >> 16);
        }
    }
    #pragma unroll
    for (int i = 0; i < 8; i++) {
        acc[i] += __shfl_xor(acc[i], 16, 64);
        acc[i] += __shfl_xor(acc[i], 32, 64);
    }
    float den = head == 0 ? den0 : head == 1 ? den1 : head == 2 ? den2 : den3;
    float rden = 1.f / den;
    float4 bA = *(const float4*)(b1 + l8 * 8), bB = *(const float4*)(b1 + l8 * 8 + 4);
    float v[8];
    v[0] = acc[0] * rden + bA.x; v[1] = acc[1] * rden + bA.y;
    v[2] = acc[2] * rden + bA.z; v[3] = acc[3] * rden + bA.w;
    v[4] = acc[4] * rden + bB.x; v[5] = acc[5] * rden + bB.y;
    v[6] = acc[6] * rden + bB.z; v[7] = acc[7] * rden + bB.w;
    float s8 = 0.f;
    #pragma unroll
    for (int i = 0; i < 8; i++) { v[i] = v[i] > 0.f ? v[i] : expf(v[i]) - 1.f; s8 += v[i]; }
    float mu = wave_sum(s8) * (1.f / 512.f);       // each chan counted 4x
    float vr = 0.f;
    #pragma unroll
    for (int i = 0; i < 8; i++) { v[i] -= mu; vr += v[i] * v[i]; }
    float rs = rsqrtf(wave_sum(vr) * (1.f / 512.f) + 1e-5f);
    if (grp == 0) {
        float4 gA = *(const float4*)(g + l8 * 8),  gB = *(const float4*)(g + l8 * 8 + 4);
        float4 eA = *(const float4*)(be + l8 * 8), eB = *(const float4*)(be + l8 * 8 + 4);
        u16 o[8] = {f2bf(v[0] * rs * gA.x + eA.x), f2bf(v[1] * rs * gA.y + eA.y),
                    f2bf(v[2] * rs * gA.z + eA.z), f2bf(v[3] * rs * gA.w + eA.w),
                    f2bf(v[4] * rs * gB.x + eB.x), f2bf(v[5] * rs * gB.y + eB.y),
                    f2bf(v[6] * rs * gB.z + eB.z), f2bf(v[7] * rs * gB.w + eB.w)};
        *(uint4*)(BOb + (size_t)node * D1 + l8 * 8) = *(uint4*)o;
    }
}

// ---------------- layer 2: gather + softmax + head-mean + LN + log_softmax -> f32 out
__global__ __launch_bounds__(256) void gat_fused2(const int* __restrict__ rowptr,
                                                  const u16* __restrict__ esrc,
                                                  const float* __restrict__ ssrc,
                                                  const float* __restrict__ sdst,
                                                  const u16* __restrict__ BH,
                                                  const float* __restrict__ b2,
                                                  const float* __restrict__ g,
                                                  const float* __restrict__ be,
                                                  float* __restrict__ out) {
    __shared__ int   s_src[4][64];
    __shared__ uint2 s_al[4][64];
    __shared__ float scr3[4][3][160];
    int wid = threadIdx.x >> 6, lane = threadIdx.x & 63;
    int node = blockIdx.x * 4 + wid;
    int grp = lane / 20;                    // 3 => idle in phase B
    int glane = lane - grp * 20;
    int head = glane / 5;                   // chans glane*8..+7
    float4 sd = *(const float4*)(sdst + node * 4);
    int beg = rowptr[node], end = rowptr[node + 1];
    float m0 = -INFINITY, m1 = -INFINITY, m2 = -INFINITY, m3 = -INFINITY;
    float den0 = 0.f, den1 = 0.f, den2 = 0.f, den3 = 0.f;
    float acc[8];
    #pragma unroll
    for (int i = 0; i < 8; i++) acc[i] = 0.f;

    for (int tb = beg; tb < end; tb += 64) {
        PHASE_A(s_src, s_al)
        float scl = head == 0 ? sc0 : head == 1 ? sc1 : head == 2 ? sc2 : sc3;
        #pragma unroll
        for (int i = 0; i < 8; i++) acc[i] *= scl;
        if (grp < 3) {
            #pragma unroll 2
            for (int j = grp; j < nj; j += 3) {
                int sj = s_src[wid][j];
                uint2 pk = s_al[wid][j];
                float2 lof = unpack_h2(pk.x), hif = unpack_h2(pk.y);
                float al = head == 0 ? lof.x : head == 1 ? lof.y : head == 2 ? hif.x : hif.y;
                uint4 h = *(const uint4*)(BH + (size_t)sj * D2 + glane * 8);
                acc[0] += al * bf2f(h.x & 0xffffu); acc[1] += al * bf2f(h.x >> 16);
                acc[2] += al * bf2f(h.y & 0xffffu); acc[3] += al * bf2f(h.y >> 16);
                acc[4] += al * bf2f(h.z & 0xffffu); acc[5] += al * bf2f(h.z >> 16);
                acc[6] += al * bf2f(h.w & 0xffffu); acc[7] += al * bf2f(h.w >> 16);
            }
        }
    }
    if (grp < 3) {
        float den = head == 0 ? den0 : head == 1 ? den1 : head == 2 ? den2 : den3;
        float rden = 1.f / den;
        float4 oA = {acc[0] * rden, acc[1] * rden, acc[2] * rden, acc[3] * rden};
        float4 oB = {acc[4] * rden, acc[5] * rden, acc[6] * rden, acc[7] * rden};
        *(float4*)&scr3[wid][grp][glane * 8]     = oA;
        *(float4*)&scr3[wid][grp][glane * 8 + 4] = oB;
    }
    // wave-private LDS; no barrier needed
    bool act = lane < 40;
    int c = act ? lane : 0;
    float o = 0.f;
    if (act) {
        float s = 0.f;
        #pragma unroll
        for (int k = 0; k < 4; k++)
            #pragma unroll
            for (int gg = 0; gg < 3; gg++) s += scr3[wid][gg][c + 40 * k];
        o = 0.25f * s + b2[c];
    }
    float mu = wave_sum(act ? o : 0.f) * (1.f / 40.f);
    float dv = act ? o - mu : 0.f;
    float var = wave_sum(dv * dv) * (1.f / 40.f);
    float rs = rsqrtf(var + 1e-5f);
    float y = act ? dv * rs * g[c] + be[c] : -1e30f;
    float mx = wave_max(y);
    float ex = act ? expf(y - mx) : 0.f;
    float lse = logf(wave_sum(ex));
    if (act) out[(size_t)node * 40 + c] = y - mx - lse;
}

extern "C" void kernel_launch(void* const* d_in, const int* in_sizes, int n_in,
                              void* d_out, int out_size, void* d_ws, size_t ws_size,
                              hipStream_t stream) {
    const float* x   = (const float*)d_in[0];
    const int*   ei  = (const int*)d_in[1];
    const float* W1  = (const float*)d_in[2];
    const float* as1 = (const float*)d_in[3];
    const float* ad1 = (const float*)d_in[4];
    const float* b1  = (const float*)d_in[5];
    const float* W2  = (const float*)d_in[6];
    const float* as2 = (const float*)d_in[7];
    const float* ad2 = (const float*)d_in[8];
    const float* b2  = (const float*)d_in[9];
    const float* g0  = (const float*)d_in[10];
    const float* be0 = (const float*)d_in[11];
    const float* g1  = (const float*)d_in[12];
    const float* be1 = (const float*)d_in[13];

    float* ws = (float*)d_ws;
    // layout in float units; esrc needs ETOT u16 = 425,000 FLOATS (r7 bug: gave it 212,500)
    u16*   BH1    = (u16*)ws;                       // 50000*128 bf16 = 3,200,000 f
    u16*   BH2    = (u16*)(ws + 3200000);           // 50000*160 bf16 = 4,000,000 f
    u16*   BOb    = (u16*)(ws + 7200000);           // 50000*128 bf16 = 3,200,000 f
    float* ssrc   = ws + 10400000;                  // 200,000 f
    float* sdst   = ws + 10600000;                  // 200,000 f
    int*   rowptr = (int*)(ws + 10800000);          // 50,001 (+3 pad)
    u16*   esrc   = (u16*)(ws + 10850004);          // ETOT u16 = 425,000 f
    int*   counts = (int*)(ws + 11275004);          // 50,000
    int*   cursor = (int*)(ws + 11325004);          // 50,000 (contiguous with counts)
    u16*   Wf1    = (u16*)(ws + 11375004);          // 36,864 bf16 = 18,432 f (16B-aligned)
    u16*   Wf2    = (u16*)(ws + 11393436);          // 22,528 bf16 = 11,264 f (16B-aligned)
    // end: 11,404,700 f = 45.6 MB

    const int eb  = (ETOT + 255) / 256;
    const int nb4 = NNODES / 4;
    const int tot1 = 9 * 8 * 512, tot2 = 11 * 4 * 512;

    // ---- CSR build (graph shared by both layers) ----
    hipMemsetAsync(counts, 0, 2 * NNODES * sizeof(int), stream);
    count_k<<<eb, 256, 0, stream>>>(ei, counts);
    scan_k<<<1, 1024, 0, stream>>>(counts, rowptr);
    fill_k<<<eb, 256, 0, stream>>>(ei, rowptr, cursor, esrc);

    // ---- weight repack + composed attention-dot columns ----
    repack_all<<<(tot1 + 255) / 256, 256, 0, stream>>>(W1, as1, ad1, Wf1, FIN, D1, C1, tot1);
    repack_all<<<(tot2 + 255) / 256, 256, 0, stream>>>(W2, as2, ad2, Wf2, D1, D2, C2, tot2);

    // ================= layer 1 =================
    gemm_mfma<true, FIN, 8><<<MPAD / 64, 256, 0, stream>>>(x, Wf1, BH1, ssrc, sdst, NNODES);
    gat_fused1<<<nb4, 256, 0, stream>>>(rowptr, esrc, ssrc, sdst, BH1, b1, g0, be0, BOb);

    // ================= layer 2 =================
    gemm_mfma<false, D1, 10><<<MPAD / 64, 256, 0, stream>>>(BOb, Wf2, BH2, ssrc, sdst, NNODES);
    gat_fused2<<<nb4, 256, 0, stream>>>(rowptr, esrc, ssrc, sdst, BH2, b2, g1, be1, (float*)d_out);
}

// Round 9
// 347.072 us; speedup vs baseline: 11.9803x; 1.0439x over previous
//
#include <hip/hip_runtime.h>
#include <hip/hip_bf16.h>
#include <hip/hip_fp16.h>

#define NNODES 50000
#define MPAD   50048
#define NEDGES 800000
#define ETOT   (NEDGES + NNODES)
#define FIN    256
#define HEADS  4
#define C1     32
#define D1     128
#define C2     40
#define D2     160

typedef unsigned short u16;
typedef short v8s __attribute__((ext_vector_type(8)));
typedef float v4f __attribute__((ext_vector_type(4)));

__device__ __forceinline__ float bf2f(unsigned u) {
    union { unsigned u; float f; } x; x.u = u << 16; return x.f;
}
__device__ __forceinline__ u16 f2bf(float f) {        // RNE
    unsigned u = __float_as_uint(f);
    return (u16)((u + 0x7fff + ((u >> 16) & 1)) >> 16);
}
// fast pack: two f32 -> packed bf16 pair (round-half-up; a in low half)
__device__ __forceinline__ unsigned pk_bf16(float a, float b) {
    unsigned ua = (__float_as_uint(a) + 0x8000u) >> 16;
    unsigned ub = (__float_as_uint(b) + 0x8000u) & 0xffff0000u;
    return ub | ua;
}
__device__ __forceinline__ float wave_sum(float v) {
    #pragma unroll
    for (int m = 32; m > 0; m >>= 1) v += __shfl_xor(v, m, 64);
    return v;
}
__device__ __forceinline__ float wave_max(float v) {
    #pragma unroll
    for (int m = 32; m > 0; m >>= 1) v = fmaxf(v, __shfl_xor(v, m, 64));
    return v;
}
__device__ __forceinline__ float leaky(float x) { return fmaxf(x, 0.2f * x); }

// ---------------- repack W[K,N] f32 -> MFMA B-fragment order bf16, plus one
// extra 16-col tile: col h = W @ a_src_h (zero-extended), col 4+h = W @ a_dst_h
__global__ void repack_all(const float* __restrict__ W, const float* __restrict__ as,
                           const float* __restrict__ ad, u16* __restrict__ Wf,
                           int K, int N, int C, int total) {
    int idx = blockIdx.x * blockDim.x + threadIdx.x;
    if (idx >= total) return;
    int KS = K >> 5, NT = N >> 4;
    int j = idx & 7, lane = (idx >> 3) & 63;
    int rest = idx >> 9;
    int ks = rest % KS, nt = rest / KS;
    int k = ks * 32 + (lane >> 4) * 8 + j;
    int n16 = lane & 15;
    float val = 0.f;
    if (nt < NT) {
        val = W[(size_t)k * N + nt * 16 + n16];
    } else if (n16 < 8) {
        int h = n16 & 3;
        const float* av = (n16 < 4) ? as : ad;
        float s = 0.f;
        for (int c = 0; c < C; c++) s += W[(size_t)k * N + h * C + c] * av[h * C + c];
        val = s;
    }
    Wf[idx] = f2bf(val);
}

// ---------------- MFMA GEMM + fused attention dots
template <bool AF32, int KK, int NT>
__global__ __launch_bounds__(256) void gemm_mfma(const void* __restrict__ Aptr,
                                                 const u16* __restrict__ Wf,
                                                 u16* __restrict__ Out,
                                                 float* __restrict__ ssrc,
                                                 float* __restrict__ sdst, int M) {
    const int KS = KK / 32;
    const int NCOL = NT * 16;
    int wid = threadIdx.x >> 6, lane = threadIdx.x & 63;
    int r0 = blockIdx.x * 64 + wid * 16;
    int m = lane & 15, quad = lane >> 4;
    int row = r0 + m;
    bool rowok = row < M;

    v8s a[KS];
    if (AF32) {
        const float* ap = (const float*)Aptr + (size_t)(rowok ? row : 0) * KK + quad * 8;
        #pragma unroll
        for (int ks = 0; ks < KS; ks++) {
            if (rowok) {
                float4 fa = *(const float4*)(ap + ks * 32);
                float4 fb = *(const float4*)(ap + ks * 32 + 4);
                union { unsigned u[4]; v8s v; } c;
                c.u[0] = pk_bf16(fa.x, fa.y); c.u[1] = pk_bf16(fa.z, fa.w);
                c.u[2] = pk_bf16(fb.x, fb.y); c.u[3] = pk_bf16(fb.z, fb.w);
                a[ks] = c.v;
            } else {
                a[ks] = (v8s){0,0,0,0,0,0,0,0};
            }
        }
    } else {
        const u16* ap = (const u16*)Aptr + (size_t)(rowok ? row : 0) * KK + quad * 8;
        #pragma unroll
        for (int ks = 0; ks < KS; ks++)
            a[ks] = rowok ? *(const v8s*)(ap + ks * 32) : (v8s){0,0,0,0,0,0,0,0};
    }

    const v8s* bp0 = (const v8s*)Wf + lane;
    #pragma unroll 2
    for (int nt = 0; nt < NT; nt++) {
        v4f acc = {0.f, 0.f, 0.f, 0.f};
        const v8s* bp = bp0 + nt * KS * 64;
        #pragma unroll
        for (int ks = 0; ks < KS; ks++)
            acc = __builtin_amdgcn_mfma_f32_16x16x32_bf16(a[ks], bp[ks * 64], acc, 0, 0, 0);
        int col = nt * 16 + m;
        #pragma unroll
        for (int reg = 0; reg < 4; reg++) {
            int r = r0 + quad * 4 + reg;
            if (r < M) Out[(size_t)r * NCOL + col] = f2bf(acc[reg]);
        }
    }
    // ext tile: attention dots
    {
        v4f acc = {0.f, 0.f, 0.f, 0.f};
        const v8s* bp = bp0 + NT * KS * 64;
        #pragma unroll
        for (int ks = 0; ks < KS; ks++)
            acc = __builtin_amdgcn_mfma_f32_16x16x32_bf16(a[ks], bp[ks * 64], acc, 0, 0, 0);
        if (m < 8) {
            float* tgt = (m < 4) ? ssrc : sdst;
            int h = m & 3;
            #pragma unroll
            for (int reg = 0; reg < 4; reg++) {
                int r = r0 + quad * 4 + reg;
                if (r < M) tgt[r * 4 + h] = acc[reg];
            }
        }
    }
}

// ---------------- CSR build
__global__ void count_k(const int* __restrict__ ei, int* __restrict__ counts) {
    int t = blockIdx.x * blockDim.x + threadIdx.x;
    if (t >= ETOT) return;
    int d = (t < NEDGES) ? ei[NEDGES + t] : (t - NEDGES);
    atomicAdd(&counts[d], 1);
}

__global__ __launch_bounds__(1024) void scan_k(const int* __restrict__ counts, int* __restrict__ rowptr) {
    __shared__ int wsum[16];
    __shared__ int srun;
    const int t = threadIdx.x;
    const int lane = t & 63, wid = t >> 6;
    if (t == 0) srun = 0;
    __syncthreads();
    for (int base = 0; base < NNODES; base += 4096) {
        int i4 = base + t * 4;
        int4 v = make_int4(0, 0, 0, 0);
        if (i4 < NNODES) v = *(const int4*)(counts + i4);
        int tsum = v.x + v.y + v.z + v.w;
        int x = tsum;
        #pragma unroll
        for (int off = 1; off < 64; off <<= 1) {
            int y = __shfl_up(x, off, 64);
            if (lane >= off) x += y;
        }
        if (lane == 63) wsum[wid] = x;
        __syncthreads();
        if (wid == 0) {
            int w = (lane < 16) ? wsum[lane] : 0;
            #pragma unroll
            for (int off = 1; off < 16; off <<= 1) {
                int y = __shfl_up(w, off, 64);
                if (lane >= off) w += y;
            }
            if (lane < 16) wsum[lane] = w;
        }
        __syncthreads();
        int wbase = (wid > 0) ? wsum[wid - 1] : 0;
        int run = srun;
        int pre = run + wbase + x - tsum;
        if (i4 < NNODES) {
            rowptr[i4]     = pre;
            rowptr[i4 + 1] = pre + v.x;
            rowptr[i4 + 2] = pre + v.x + v.y;
            rowptr[i4 + 3] = pre + v.x + v.y + v.z;
        }
        __syncthreads();
        if (t == 1023) srun = run + wsum[15];
        __syncthreads();
    }
    if (t == 0) rowptr[NNODES] = srun;
}

__global__ void fill_k(const int* __restrict__ ei, const int* __restrict__ rowptr,
                       int* __restrict__ cursor, u16* __restrict__ esrc) {
    int t = blockIdx.x * blockDim.x + threadIdx.x;
    if (t >= ETOT) return;
    int s, d;
    if (t < NEDGES) { s = ei[t]; d = ei[NEDGES + t]; } else { s = t - NEDGES; d = s; }
    int pos = atomicAdd(&cursor[d], 1);
    esrc[rowptr[d] + pos] = (u16)s;
}

// phase A: max-free softmax tile (e bounded by construction; softmax is
// shift-invariant so result matches reference to fp rounding).
// p stored f32 per head in LDS (stride 65 -> conflict-free phase-B reads).
#define PHASE_A(SRC_ARR, P_ARR)                                                    \
    int nj = end - tb; if (nj > 64) nj = 64;                                       \
    bool on = lane < nj;                                                           \
    int sE = 0;                                                                    \
    if (on) { sE = esrc[tb + lane]; SRC_ARR[wid][lane] = sE; }                     \
    float4 sp = *(const float4*)(ssrc + sE * 4);                                   \
    float p0 = on ? __expf(leaky(sp.x + sd.x)) : 0.f;                              \
    float p1 = on ? __expf(leaky(sp.y + sd.y)) : 0.f;                              \
    float p2 = on ? __expf(leaky(sp.z + sd.z)) : 0.f;                              \
    float p3 = on ? __expf(leaky(sp.w + sd.w)) : 0.f;                              \
    den0 += wave_sum(p0); den1 += wave_sum(p1);                                    \
    den2 += wave_sum(p2); den3 += wave_sum(p3);                                    \
    if (on) { P_ARR[wid][0][lane] = p0; P_ARR[wid][1][lane] = p1;                  \
              P_ARR[wid][2][lane] = p2; P_ARR[wid][3][lane] = p3; }

// ---------------- layer 1: gather + softmax + bias + ELU + LN -> bf16 BOb
__global__ __launch_bounds__(256) void gat_fused1(const int* __restrict__ rowptr,
                                                  const u16* __restrict__ esrc,
                                                  const float* __restrict__ ssrc,
                                                  const float* __restrict__ sdst,
                                                  const u16* __restrict__ BH,
                                                  const float* __restrict__ b1,
                                                  const float* __restrict__ g,
                                                  const float* __restrict__ be,
                                                  u16* __restrict__ BOb) {
    __shared__ int   s_src[4][64];
    __shared__ float s_p[4][4][65];
    int wid = threadIdx.x >> 6, lane = threadIdx.x & 63;
    int node = blockIdx.x * 4 + wid;
    int l8 = lane & 15, grp = lane >> 4;
    int head = l8 >> 2;
    float4 sd = *(const float4*)(sdst + node * 4);
    int beg = rowptr[node], end = rowptr[node + 1];
    float den0 = 0.f, den1 = 0.f, den2 = 0.f, den3 = 0.f;
    float acc[8];
    #pragma unroll
    for (int i = 0; i < 8; i++) acc[i] = 0.f;

    for (int tb = beg; tb < end; tb += 64) {
        PHASE_A(s_src, s_p)
        #pragma unroll 4
        for (int j = grp; j < nj; j += 4) {
            int sj = s_src[wid][j];
            float al = s_p[wid][head][j];
            uint4 h = *(const uint4*)(BH + (size_t)sj * D1 + l8 * 8);
            acc[0] += al * bf2f(h.x & 0xffffu); acc[1] += al * bf2f(h.x >> 16);
            acc[2] += al * bf2f(h.y & 0xffffu); acc[3] += al * bf2f(h.y >> 16);
            acc[4] += al * bf2f(h.z & 0xffffu); acc[5] += al * bf2f(h.z >> 16);
            acc[6] += al * bf2f(h.w & 0xffffu); acc[7] += al * bf2f(h.w >> 16);
        }
    }
    #pragma unroll
    for (int i = 0; i < 8; i++) {
        acc[i] += __shfl_xor(acc[i], 16, 64);
        acc[i] += __shfl_xor(acc[i], 32, 64);
    }
    float den = head == 0 ? den0 : head == 1 ? den1 : head == 2 ? den2 : den3;
    float rden = 1.f / den;
    float4 bA = *(const float4*)(b1 + l8 * 8), bB = *(const float4*)(b1 + l8 * 8 + 4);
    float v[8];
    v[0] = acc[0] * rden + bA.x; v[1] = acc[1] * rden + bA.y;
    v[2] = acc[2] * rden + bA.z; v[3] = acc[3] * rden + bA.w;
    v[4] = acc[4] * rden + bB.x; v[5] = acc[5] * rden + bB.y;
    v[6] = acc[6] * rden + bB.z; v[7] = acc[7] * rden + bB.w;
    float s8 = 0.f;
    #pragma unroll
    for (int i = 0; i < 8; i++) { v[i] = v[i] > 0.f ? v[i] : __expf(v[i]) - 1.f; s8 += v[i]; }
    float mu = wave_sum(s8) * (1.f / 512.f);       // each chan counted 4x
    float vr = 0.f;
    #pragma unroll
    for (int i = 0; i < 8; i++) { v[i] -= mu; vr += v[i] * v[i]; }
    float rs = rsqrtf(wave_sum(vr) * (1.f / 512.f) + 1e-5f);
    if (grp == 0) {
        float4 gA = *(const float4*)(g + l8 * 8),  gB = *(const float4*)(g + l8 * 8 + 4);
        float4 eA = *(const float4*)(be + l8 * 8), eB = *(const float4*)(be + l8 * 8 + 4);
        u16 o[8] = {f2bf(v[0] * rs * gA.x + eA.x), f2bf(v[1] * rs * gA.y + eA.y),
                    f2bf(v[2] * rs * gA.z + eA.z), f2bf(v[3] * rs * gA.w + eA.w),
                    f2bf(v[4] * rs * gB.x + eB.x), f2bf(v[5] * rs * gB.y + eB.y),
                    f2bf(v[6] * rs * gB.z + eB.z), f2bf(v[7] * rs * gB.w + eB.w)};
        *(uint4*)(BOb + (size_t)node * D1 + l8 * 8) = *(uint4*)o;
    }
}

// ---------------- layer 2: gather + softmax + head-mean + LN + log_softmax -> f32 out
__global__ __launch_bounds__(256) void gat_fused2(const int* __restrict__ rowptr,
                                                  const u16* __restrict__ esrc,
                                                  const float* __restrict__ ssrc,
                                                  const float* __restrict__ sdst,
                                                  const u16* __restrict__ BH,
                                                  const float* __restrict__ b2,
                                                  const float* __restrict__ g,
                                                  const float* __restrict__ be,
                                                  float* __restrict__ out) {
    __shared__ int   s_src[4][64];
    __shared__ float s_p[4][4][65];
    __shared__ float scr3[4][3][160];
    int wid = threadIdx.x >> 6, lane = threadIdx.x & 63;
    int node = blockIdx.x * 4 + wid;
    int grp = lane / 20;                    // 3 => idle in phase B
    int glane = lane - grp * 20;
    int head = glane / 5;                   // chans glane*8..+7
    float4 sd = *(const float4*)(sdst + node * 4);
    int beg = rowptr[node], end = rowptr[node + 1];
    float den0 = 0.f, den1 = 0.f, den2 = 0.f, den3 = 0.f;
    float acc[8];
    #pragma unroll
    for (int i = 0; i < 8; i++) acc[i] = 0.f;

    for (int tb = beg; tb < end; tb += 64) {
        PHASE_A(s_src, s_p)
        if (grp < 3) {
            #pragma unroll 4
            for (int j = grp; j < nj; j += 3) {
                int sj = s_src[wid][j];
                float al = s_p[wid][head][j];
                uint4 h = *(const uint4*)(BH + (size_t)sj * D2 + glane * 8);
                acc[0] += al * bf2f(h.x & 0xffffu); acc[1] += al * bf2f(h.x >> 16);
                acc[2] += al * bf2f(h.y & 0xffffu); acc[3] += al * bf2f(h.y >> 16);
                acc[4] += al * bf2f(h.z & 0xffffu); acc[5] += al * bf2f(h.z >> 16);
                acc[6] += al * bf2f(h.w & 0xffffu); acc[7] += al * bf2f(h.w >> 16);
            }
        }
    }
    if (grp < 3) {
        float den = head == 0 ? den0 : head == 1 ? den1 : head == 2 ? den2 : den3;
        float rden = 1.f / den;
        float4 oA = {acc[0] * rden, acc[1] * rden, acc[2] * rden, acc[3] * rden};
        float4 oB = {acc[4] * rden, acc[5] * rden, acc[6] * rden, acc[7] * rden};
        *(float4*)&scr3[wid][grp][glane * 8]     = oA;
        *(float4*)&scr3[wid][grp][glane * 8 + 4] = oB;
    }
    // wave-private LDS; no barrier needed
    bool act = lane < 40;
    int c = act ? lane : 0;
    float o = 0.f;
    if (act) {
        float s = 0.f;
        #pragma unroll
        for (int k = 0; k < 4; k++)
            #pragma unroll
            for (int gg = 0; gg < 3; gg++) s += scr3[wid][gg][c + 40 * k];
        o = 0.25f * s + b2[c];
    }
    float mu = wave_sum(act ? o : 0.f) * (1.f / 40.f);
    float dv = act ? o - mu : 0.f;
    float var = wave_sum(dv * dv) * (1.f / 40.f);
    float rs = rsqrtf(var + 1e-5f);
    float y = act ? dv * rs * g[c] + be[c] : -1e30f;
    float mx = wave_max(y);
    float ex = act ? __expf(y - mx) : 0.f;
    float lse = __logf(wave_sum(ex));
    if (act) out[(size_t)node * 40 + c] = y - mx - lse;
}

extern "C" void kernel_launch(void* const* d_in, const int* in_sizes, int n_in,
                              void* d_out, int out_size, void* d_ws, size_t ws_size,
                              hipStream_t stream) {
    const float* x   = (const float*)d_in[0];
    const int*   ei  = (const int*)d_in[1];
    const float* W1  = (const float*)d_in[2];
    const float* as1 = (const float*)d_in[3];
    const float* ad1 = (const float*)d_in[4];
    const float* b1  = (const float*)d_in[5];
    const float* W2  = (const float*)d_in[6];
    const float* as2 = (const float*)d_in[7];
    const float* ad2 = (const float*)d_in[8];
    const float* b2  = (const float*)d_in[9];
    const float* g0  = (const float*)d_in[10];
    const float* be0 = (const float*)d_in[11];
    const float* g1  = (const float*)d_in[12];
    const float* be1 = (const float*)d_in[13];

    float* ws = (float*)d_ws;
    u16*   BH1    = (u16*)ws;                       // 50000*128 bf16 = 3,200,000 f
    u16*   BH2    = (u16*)(ws + 3200000);           // 50000*160 bf16 = 4,000,000 f
    u16*   BOb    = (u16*)(ws + 7200000);           // 50000*128 bf16 = 3,200,000 f
    float* ssrc   = ws + 10400000;                  // 200,000 f
    float* sdst   = ws + 10600000;                  // 200,000 f
    int*   rowptr = (int*)(ws + 10800000);          // 50,001 (+3 pad)
    u16*   esrc   = (u16*)(ws + 10850004);          // ETOT u16 = 425,000 f
    int*   counts = (int*)(ws + 11275004);          // 50,000
    int*   cursor = (int*)(ws + 11325004);          // 50,000 (contiguous with counts)
    u16*   Wf1    = (u16*)(ws + 11375004);          // 36,864 bf16
    u16*   Wf2    = (u16*)(ws + 11393436);          // 22,528 bf16

    const int eb  = (ETOT + 255) / 256;
    const int nb4 = NNODES / 4;
    const int tot1 = 9 * 8 * 512, tot2 = 11 * 4 * 512;

    // ---- CSR build (graph shared by both layers) ----
    hipMemsetAsync(counts, 0, 2 * NNODES * sizeof(int), stream);
    count_k<<<eb, 256, 0, stream>>>(ei, counts);
    scan_k<<<1, 1024, 0, stream>>>(counts, rowptr);
    fill_k<<<eb, 256, 0, stream>>>(ei, rowptr, cursor, esrc);

    // ---- weight repack + composed attention-dot columns ----
    repack_all<<<(tot1 + 255) / 256, 256, 0, stream>>>(W1, as1, ad1, Wf1, FIN, D1, C1, tot1);
    repack_all<<<(tot2 + 255) / 256, 256, 0, stream>>>(W2, as2, ad2, Wf2, D1, D2, C2, tot2);

    // ================= layer 1 =================
    gemm_mfma<true, FIN, 8><<<MPAD / 64, 256, 0, stream>>>(x, Wf1, BH1, ssrc, sdst, NNODES);
    gat_fused1<<<nb4, 256, 0, stream>>>(rowptr, esrc, ssrc, sdst, BH1, b1, g0, be0, BOb);

    // ================= layer 2 =================
    gemm_mfma<false, D1, 10><<<MPAD / 64, 256, 0, stream>>>(BOb, Wf2, BH2, ssrc, sdst, NNODES);
    gat_fused2<<<nb4, 256, 0, stream>>>(rowptr, esrc, ssrc, sdst, BH2, b2, g1, be1, (float*)d_out);
}

// Round 10
// 338.194 us; speedup vs baseline: 12.2948x; 1.0263x over previous
//
#include <hip/hip_runtime.h>
#include <hip/hip_bf16.h>
#include <hip/hip_fp16.h>

#define NNODES 50000
#define MPAD   50048
#define NEDGES 800000
#define ETOT   (NEDGES + NNODES)
#define FIN    256
#define HEADS  4
#define C1     32
#define D1     128
#define C2     40
#define D2     160

typedef unsigned short u16;
typedef short v8s __attribute__((ext_vector_type(8)));
typedef float v4f __attribute__((ext_vector_type(4)));

__device__ __forceinline__ float bf2f(unsigned u) {
    union { unsigned u; float f; } x; x.u = u << 16; return x.f;
}
__device__ __forceinline__ u16 f2bf(float f) {        // RNE
    unsigned u = __float_as_uint(f);
    return (u16)((u + 0x7fff + ((u >> 16) & 1)) >> 16);
}
// fast pack: two f32 -> packed bf16 pair (round-half-up; a in low half)
__device__ __forceinline__ unsigned pk_bf16(float a, float b) {
    unsigned ua = (__float_as_uint(a) + 0x8000u) >> 16;
    unsigned ub = (__float_as_uint(b) + 0x8000u) & 0xffff0000u;
    return ub | ua;
}
__device__ __forceinline__ float wave_sum(float v) {
    #pragma unroll
    for (int m = 32; m > 0; m >>= 1) v += __shfl_xor(v, m, 64);
    return v;
}
__device__ __forceinline__ float wave_max(float v) {
    #pragma unroll
    for (int m = 32; m > 0; m >>= 1) v = fmaxf(v, __shfl_xor(v, m, 64));
    return v;
}
__device__ __forceinline__ float leaky(float x) { return fmaxf(x, 0.2f * x); }

// ---------------- repack W[K,N] f32 -> MFMA B-fragment order bf16, plus one
// extra 16-col tile: col h = W @ a_src_h (zero-extended), col 4+h = W @ a_dst_h
__global__ void repack_all(const float* __restrict__ W, const float* __restrict__ as,
                           const float* __restrict__ ad, u16* __restrict__ Wf,
                           int K, int N, int C, int total) {
    int idx = blockIdx.x * blockDim.x + threadIdx.x;
    if (idx >= total) return;
    int KS = K >> 5, NT = N >> 4;
    int j = idx & 7, lane = (idx >> 3) & 63;
    int rest = idx >> 9;
    int ks = rest % KS, nt = rest / KS;
    int k = ks * 32 + (lane >> 4) * 8 + j;
    int n16 = lane & 15;
    float val = 0.f;
    if (nt < NT) {
        val = W[(size_t)k * N + nt * 16 + n16];
    } else if (n16 < 8) {
        int h = n16 & 3;
        const float* av = (n16 < 4) ? as : ad;
        float s = 0.f;
        for (int c = 0; c < C; c++) s += W[(size_t)k * N + h * C + c] * av[h * C + c];
        val = s;
    }
    Wf[idx] = f2bf(val);
}

// ---------------- MFMA GEMM + fused attention dots
template <bool AF32, int KK, int NT>
__global__ __launch_bounds__(256) void gemm_mfma(const void* __restrict__ Aptr,
                                                 const u16* __restrict__ Wf,
                                                 u16* __restrict__ Out,
                                                 float* __restrict__ ssrc,
                                                 float* __restrict__ sdst, int M) {
    const int KS = KK / 32;
    const int NCOL = NT * 16;
    int wid = threadIdx.x >> 6, lane = threadIdx.x & 63;
    int r0 = blockIdx.x * 64 + wid * 16;
    int m = lane & 15, quad = lane >> 4;
    int row = r0 + m;
    bool rowok = row < M;

    v8s a[KS];
    if (AF32) {
        const float* ap = (const float*)Aptr + (size_t)(rowok ? row : 0) * KK + quad * 8;
        #pragma unroll
        for (int ks = 0; ks < KS; ks++) {
            if (rowok) {
                float4 fa = *(const float4*)(ap + ks * 32);
                float4 fb = *(const float4*)(ap + ks * 32 + 4);
                union { unsigned u[4]; v8s v; } c;
                c.u[0] = pk_bf16(fa.x, fa.y); c.u[1] = pk_bf16(fa.z, fa.w);
                c.u[2] = pk_bf16(fb.x, fb.y); c.u[3] = pk_bf16(fb.z, fb.w);
                a[ks] = c.v;
            } else {
                a[ks] = (v8s){0,0,0,0,0,0,0,0};
            }
        }
    } else {
        const u16* ap = (const u16*)Aptr + (size_t)(rowok ? row : 0) * KK + quad * 8;
        #pragma unroll
        for (int ks = 0; ks < KS; ks++)
            a[ks] = rowok ? *(const v8s*)(ap + ks * 32) : (v8s){0,0,0,0,0,0,0,0};
    }

    const v8s* bp0 = (const v8s*)Wf + lane;
    #pragma unroll 2
    for (int nt = 0; nt < NT; nt++) {
        v4f acc = {0.f, 0.f, 0.f, 0.f};
        const v8s* bp = bp0 + nt * KS * 64;
        #pragma unroll
        for (int ks = 0; ks < KS; ks++)
            acc = __builtin_amdgcn_mfma_f32_16x16x32_bf16(a[ks], bp[ks * 64], acc, 0, 0, 0);
        int col = nt * 16 + m;
        #pragma unroll
        for (int reg = 0; reg < 4; reg++) {
            int r = r0 + quad * 4 + reg;
            if (r < M) Out[(size_t)r * NCOL + col] = f2bf(acc[reg]);
        }
    }
    // ext tile: attention dots
    {
        v4f acc = {0.f, 0.f, 0.f, 0.f};
        const v8s* bp = bp0 + NT * KS * 64;
        #pragma unroll
        for (int ks = 0; ks < KS; ks++)
            acc = __builtin_amdgcn_mfma_f32_16x16x32_bf16(a[ks], bp[ks * 64], acc, 0, 0, 0);
        if (m < 8) {
            float* tgt = (m < 4) ? ssrc : sdst;
            int h = m & 3;
            #pragma unroll
            for (int reg = 0; reg < 4; reg++) {
                int r = r0 + quad * 4 + reg;
                if (r < M) tgt[r * 4 + h] = acc[reg];
            }
        }
    }
}

// ---------------- CSR build
__global__ void count_k(const int* __restrict__ ei, int* __restrict__ counts) {
    int t = blockIdx.x * blockDim.x + threadIdx.x;
    if (t >= ETOT) return;
    int d = (t < NEDGES) ? ei[NEDGES + t] : (t - NEDGES);
    atomicAdd(&counts[d], 1);
}

__global__ __launch_bounds__(1024) void scan_k(const int* __restrict__ counts, int* __restrict__ rowptr) {
    __shared__ int wsum[16];
    __shared__ int srun;
    const int t = threadIdx.x;
    const int lane = t & 63, wid = t >> 6;
    if (t == 0) srun = 0;
    __syncthreads();
    for (int base = 0; base < NNODES; base += 4096) {
        int i4 = base + t * 4;
        int4 v = make_int4(0, 0, 0, 0);
        if (i4 < NNODES) v = *(const int4*)(counts + i4);
        int tsum = v.x + v.y + v.z + v.w;
        int x = tsum;
        #pragma unroll
        for (int off = 1; off < 64; off <<= 1) {
            int y = __shfl_up(x, off, 64);
            if (lane >= off) x += y;
        }
        if (lane == 63) wsum[wid] = x;
        __syncthreads();
        if (wid == 0) {
            int w = (lane < 16) ? wsum[lane] : 0;
            #pragma unroll
            for (int off = 1; off < 16; off <<= 1) {
                int y = __shfl_up(w, off, 64);
                if (lane >= off) w += y;
            }
            if (lane < 16) wsum[lane] = w;
        }
        __syncthreads();
        int wbase = (wid > 0) ? wsum[wid - 1] : 0;
        int run = srun;
        int pre = run + wbase + x - tsum;
        if (i4 < NNODES) {
            rowptr[i4]     = pre;
            rowptr[i4 + 1] = pre + v.x;
            rowptr[i4 + 2] = pre + v.x + v.y;
            rowptr[i4 + 3] = pre + v.x + v.y + v.z;
        }
        __syncthreads();
        if (t == 1023) srun = run + wsum[15];
        __syncthreads();
    }
    if (t == 0) rowptr[NNODES] = srun;
}

__global__ void fill_k(const int* __restrict__ ei, const int* __restrict__ rowptr,
                       int* __restrict__ cursor, u16* __restrict__ esrc) {
    int t = blockIdx.x * blockDim.x + threadIdx.x;
    if (t >= ETOT) return;
    int s, d;
    if (t < NEDGES) { s = ei[t]; d = ei[NEDGES + t]; } else { s = t - NEDGES; d = s; }
    int pos = atomicAdd(&cursor[d], 1);
    esrc[rowptr[d] + pos] = (u16)s;
}

// phase A: 16-edge tile, head-parallel. lane = hh*16 + jj computes ONE p.
// den reduced over the 16-lane subgroup (4-step), accumulated per lane.
// max-free softmax (e bounded; shift-invariance) — exact vs reference to fp rounding.
#define PHASE_A16(SRC_ARR, P_ARR)                                                  \
    int nj = end - tb; if (nj > 16) nj = 16;                                       \
    bool on = jj < nj;                                                             \
    int sE = on ? (int)esrc[tb + jj] : 0;                                          \
    if (on && hh == 0) SRC_ARR[wid][jj] = sE;                                      \
    float p = on ? __expf(leaky(ssrc[sE * 4 + hh] + sdh)) : 0.f;                   \
    float tsum = p;                                                                \
    tsum += __shfl_xor(tsum, 1, 64); tsum += __shfl_xor(tsum, 2, 64);              \
    tsum += __shfl_xor(tsum, 4, 64); tsum += __shfl_xor(tsum, 8, 64);              \
    den += tsum;                                                                   \
    if (on) P_ARR[wid][hh][jj] = p;

// ---------------- layer 1: gather + softmax + bias + ELU + LN -> bf16 BOb
__global__ __launch_bounds__(256) void gat_fused1(const int* __restrict__ rowptr,
                                                  const u16* __restrict__ esrc,
                                                  const float* __restrict__ ssrc,
                                                  const float* __restrict__ sdst,
                                                  const u16* __restrict__ BH,
                                                  const float* __restrict__ b1,
                                                  const float* __restrict__ g,
                                                  const float* __restrict__ be,
                                                  u16* __restrict__ BOb) {
    __shared__ int   s_src[4][16];
    __shared__ float s_p[4][4][16];
    __shared__ float s_den[4][4];
    int wid = threadIdx.x >> 6, lane = threadIdx.x & 63;
    int node = blockIdx.x * 4 + wid;
    int jj = lane & 15, hh = lane >> 4;
    int l8 = lane & 15, grp = lane >> 4;
    int head = l8 >> 2;
    float sdh = sdst[node * 4 + hh];
    int beg = rowptr[node], end = rowptr[node + 1];
    float den = 0.f;
    float acc[8];
    #pragma unroll
    for (int i = 0; i < 8; i++) acc[i] = 0.f;

    for (int tb = beg; tb < end; tb += 16) {
        PHASE_A16(s_src, s_p)
        #pragma unroll 4
        for (int j = grp; j < nj; j += 4) {
            int sj = s_src[wid][j];
            float al = s_p[wid][head][j];
            uint4 h = *(const uint4*)(BH + (size_t)sj * D1 + l8 * 8);
            acc[0] += al * bf2f(h.x & 0xffffu); acc[1] += al * bf2f(h.x >> 16);
            acc[2] += al * bf2f(h.y & 0xffffu); acc[3] += al * bf2f(h.y >> 16);
            acc[4] += al * bf2f(h.z & 0xffffu); acc[5] += al * bf2f(h.z >> 16);
            acc[6] += al * bf2f(h.w & 0xffffu); acc[7] += al * bf2f(h.w >> 16);
        }
    }
    if (jj == 0) s_den[wid][hh] = den;      // finalize per-head denominators
    #pragma unroll
    for (int i = 0; i < 8; i++) {
        acc[i] += __shfl_xor(acc[i], 16, 64);
        acc[i] += __shfl_xor(acc[i], 32, 64);
    }
    float rden = 1.f / s_den[wid][head];
    float4 bA = *(const float4*)(b1 + l8 * 8), bB = *(const float4*)(b1 + l8 * 8 + 4);
    float v[8];
    v[0] = acc[0] * rden + bA.x; v[1] = acc[1] * rden + bA.y;
    v[2] = acc[2] * rden + bA.z; v[3] = acc[3] * rden + bA.w;
    v[4] = acc[4] * rden + bB.x; v[5] = acc[5] * rden + bB.y;
    v[6] = acc[6] * rden + bB.z; v[7] = acc[7] * rden + bB.w;
    float s8 = 0.f;
    #pragma unroll
    for (int i = 0; i < 8; i++) { v[i] = v[i] > 0.f ? v[i] : __expf(v[i]) - 1.f; s8 += v[i]; }
    float mu = wave_sum(s8) * (1.f / 512.f);       // each chan counted 4x
    float vr = 0.f;
    #pragma unroll
    for (int i = 0; i < 8; i++) { v[i] -= mu; vr += v[i] * v[i]; }
    float rs = rsqrtf(wave_sum(vr) * (1.f / 512.f) + 1e-5f);
    if (grp == 0) {
        float4 gA = *(const float4*)(g + l8 * 8),  gB = *(const float4*)(g + l8 * 8 + 4);
        float4 eA = *(const float4*)(be + l8 * 8), eB = *(const float4*)(be + l8 * 8 + 4);
        u16 o[8] = {f2bf(v[0] * rs * gA.x + eA.x), f2bf(v[1] * rs * gA.y + eA.y),
                    f2bf(v[2] * rs * gA.z + eA.z), f2bf(v[3] * rs * gA.w + eA.w),
                    f2bf(v[4] * rs * gB.x + eB.x), f2bf(v[5] * rs * gB.y + eB.y),
                    f2bf(v[6] * rs * gB.z + eB.z), f2bf(v[7] * rs * gB.w + eB.w)};
        *(uint4*)(BOb + (size_t)node * D1 + l8 * 8) = *(uint4*)o;
    }
}

// ---------------- layer 2: gather + softmax + head-mean + LN + log_softmax -> f32 out
__global__ __launch_bounds__(256) void gat_fused2(const int* __restrict__ rowptr,
                                                  const u16* __restrict__ esrc,
                                                  const float* __restrict__ ssrc,
                                                  const float* __restrict__ sdst,
                                                  const u16* __restrict__ BH,
                                                  const float* __restrict__ b2,
                                                  const float* __restrict__ g,
                                                  const float* __restrict__ be,
                                                  float* __restrict__ out) {
    __shared__ int   s_src[4][16];
    __shared__ float s_p[4][4][16];
    __shared__ float s_den[4][4];
    __shared__ float scr3[4][3][160];
    int wid = threadIdx.x >> 6, lane = threadIdx.x & 63;
    int node = blockIdx.x * 4 + wid;
    int jj = lane & 15, hh = lane >> 4;
    int grp = lane / 20;                    // 3 => idle in phase B
    int glane = lane - grp * 20;
    int head = glane / 5;                   // chans glane*8..+7
    float sdh = sdst[node * 4 + hh];
    int beg = rowptr[node], end = rowptr[node + 1];
    float den = 0.f;
    float acc[8];
    #pragma unroll
    for (int i = 0; i < 8; i++) acc[i] = 0.f;

    for (int tb = beg; tb < end; tb += 16) {
        PHASE_A16(s_src, s_p)
        if (grp < 3) {
            #pragma unroll 4
            for (int j = grp; j < nj; j += 3) {
                int sj = s_src[wid][j];
                float al = s_p[wid][head][j];
                uint4 h = *(const uint4*)(BH + (size_t)sj * D2 + glane * 8);
                acc[0] += al * bf2f(h.x & 0xffffu); acc[1] += al * bf2f(h.x >> 16);
                acc[2] += al * bf2f(h.y & 0xffffu); acc[3] += al * bf2f(h.y >> 16);
                acc[4] += al * bf2f(h.z & 0xffffu); acc[5] += al * bf2f(h.z >> 16);
                acc[6] += al * bf2f(h.w & 0xffffu); acc[7] += al * bf2f(h.w >> 16);
            }
        }
    }
    if (jj == 0) s_den[wid][hh] = den;
    if (grp < 3) {
        float rden = 1.f / s_den[wid][head];
        float4 oA = {acc[0] * rden, acc[1] * rden, acc[2] * rden, acc[3] * rden};
        float4 oB = {acc[4] * rden, acc[5] * rden, acc[6] * rden, acc[7] * rden};
        *(float4*)&scr3[wid][grp][glane * 8]     = oA;
        *(float4*)&scr3[wid][grp][glane * 8 + 4] = oB;
    }
    // wave-private LDS; no barrier needed
    bool act = lane < 40;
    int c = act ? lane : 0;
    float o = 0.f;
    if (act) {
        float s = 0.f;
        #pragma unroll
        for (int k = 0; k < 4; k++)
            #pragma unroll
            for (int gg = 0; gg < 3; gg++) s += scr3[wid][gg][c + 40 * k];
        o = 0.25f * s + b2[c];
    }
    float mu = wave_sum(act ? o : 0.f) * (1.f / 40.f);
    float dv = act ? o - mu : 0.f;
    float var = wave_sum(dv * dv) * (1.f / 40.f);
    float rs = rsqrtf(var + 1e-5f);
    float y = act ? dv * rs * g[c] + be[c] : -1e30f;
    float mx = wave_max(y);
    float ex = act ? __expf(y - mx) : 0.f;
    float lse = __logf(wave_sum(ex));
    if (act) out[(size_t)node * 40 + c] = y - mx - lse;
}

extern "C" void kernel_launch(void* const* d_in, const int* in_sizes, int n_in,
                              void* d_out, int out_size, void* d_ws, size_t ws_size,
                              hipStream_t stream) {
    const float* x   = (const float*)d_in[0];
    const int*   ei  = (const int*)d_in[1];
    const float* W1  = (const float*)d_in[2];
    const float* as1 = (const float*)d_in[3];
    const float* ad1 = (const float*)d_in[4];
    const float* b1  = (const float*)d_in[5];
    const float* W2  = (const float*)d_in[6];
    const float* as2 = (const float*)d_in[7];
    const float* ad2 = (const float*)d_in[8];
    const float* b2  = (const float*)d_in[9];
    const float* g0  = (const float*)d_in[10];
    const float* be0 = (const float*)d_in[11];
    const float* g1  = (const float*)d_in[12];
    const float* be1 = (const float*)d_in[13];

    float* ws = (float*)d_ws;
    u16*   BH1    = (u16*)ws;                       // 50000*128 bf16 = 3,200,000 f
    u16*   BH2    = (u16*)(ws + 3200000);           // 50000*160 bf16 = 4,000,000 f
    u16*   BOb    = (u16*)(ws + 7200000);           // 50000*128 bf16 = 3,200,000 f
    float* ssrc   = ws + 10400000;                  // 200,000 f
    float* sdst   = ws + 10600000;                  // 200,000 f
    int*   rowptr = (int*)(ws + 10800000);          // 50,001 (+3 pad)
    u16*   esrc   = (u16*)(ws + 10850004);          // ETOT u16 = 425,000 f
    int*   counts = (int*)(ws + 11275004);          // 50,000
    int*   cursor = (int*)(ws + 11325004);          // 50,000 (contiguous with counts)
    u16*   Wf1    = (u16*)(ws + 11375004);          // 36,864 bf16
    u16*   Wf2    = (u16*)(ws + 11393436);          // 22,528 bf16

    const int eb  = (ETOT + 255) / 256;
    const int nb4 = NNODES / 4;
    const int tot1 = 9 * 8 * 512, tot2 = 11 * 4 * 512;

    // ---- CSR build (graph shared by both layers) ----
    hipMemsetAsync(counts, 0, 2 * NNODES * sizeof(int), stream);
    count_k<<<eb, 256, 0, stream>>>(ei, counts);
    scan_k<<<1, 1024, 0, stream>>>(counts, rowptr);
    fill_k<<<eb, 256, 0, stream>>>(ei, rowptr, cursor, esrc);

    // ---- weight repack + composed attention-dot columns ----
    repack_all<<<(tot1 + 255) / 256, 256, 0, stream>>>(W1, as1, ad1, Wf1, FIN, D1, C1, tot1);
    repack_all<<<(tot2 + 255) / 256, 256, 0, stream>>>(W2, as2, ad2, Wf2, D1, D2, C2, tot2);

    // ================= layer 1 =================
    gemm_mfma<true, FIN, 8><<<MPAD / 64, 256, 0, stream>>>(x, Wf1, BH1, ssrc, sdst, NNODES);
    gat_fused1<<<nb4, 256, 0, stream>>>(rowptr, esrc, ssrc, sdst, BH1, b1, g0, be0, BOb);

    // ================= layer 2 =================
    gemm_mfma<false, D1, 10><<<MPAD / 64, 256, 0, stream>>>(BOb, Wf2, BH2, ssrc, sdst, NNODES);
    gat_fused2<<<nb4, 256, 0, stream>>>(rowptr, esrc, ssrc, sdst, BH2, b2, g1, be1, (float*)d_out);
}

// Round 11
// 309.231 us; speedup vs baseline: 13.4464x; 1.0937x over previous
//
#include <hip/hip_runtime.h>
#include <hip/hip_bf16.h>
#include <hip/hip_fp16.h>

#define NNODES 50000
#define MPAD   50048
#define NEDGES 800000
#define ETOT   (NEDGES + NNODES)
#define FIN    256
#define HEADS  4
#define C1     32
#define D1     128
#define C2     40
#define D2     160

#define CB  ((ETOT + 255) / 256)     // 3321 count/fill blocks
#define RB1 144                       // repack1 blocks (36864/256)
#define RB2 88                        // repack2 blocks (22528/256)
#define GB1 (MPAD / 64)               // 782 gemm1 blocks

typedef unsigned short u16;
typedef short v8s __attribute__((ext_vector_type(8)));
typedef float v4f __attribute__((ext_vector_type(4)));

__device__ __forceinline__ float bf2f(unsigned u) {
    union { unsigned u; float f; } x; x.u = u << 16; return x.f;
}
__device__ __forceinline__ u16 f2bf(float f) {        // RNE
    unsigned u = __float_as_uint(f);
    return (u16)((u + 0x7fff + ((u >> 16) & 1)) >> 16);
}
__device__ __forceinline__ unsigned pk_bf16(float a, float b) {
    unsigned ua = (__float_as_uint(a) + 0x8000u) >> 16;
    unsigned ub = (__float_as_uint(b) + 0x8000u) & 0xffff0000u;
    return ub | ua;
}
__device__ __forceinline__ float wave_sum(float v) {
    #pragma unroll
    for (int m = 32; m > 0; m >>= 1) v += __shfl_xor(v, m, 64);
    return v;
}
// dual reduction: one interleaved chain (ILP 2, half the serial latency)
__device__ __forceinline__ void wave_sum2(float& a, float& b) {
    #pragma unroll
    for (int m = 32; m > 0; m >>= 1) {
        a += __shfl_xor(a, m, 64);
        b += __shfl_xor(b, m, 64);
    }
}
__device__ __forceinline__ float leaky(float x) { return fmaxf(x, 0.2f * x); }

// ---------------- repack W[K,N] f32 -> MFMA B-fragment order bf16, plus ext
// 16-col tile: col h = W @ a_src_h, col 4+h = W @ a_dst_h
__device__ __forceinline__ void repack_body(const float* __restrict__ W,
                                            const float* __restrict__ as,
                                            const float* __restrict__ ad,
                                            u16* __restrict__ Wf,
                                            int K, int N, int C, int total, int idx) {
    if (idx >= total) return;
    int KS = K >> 5, NT = N >> 4;
    int j = idx & 7, lane = (idx >> 3) & 63;
    int rest = idx >> 9;
    int ks = rest % KS, nt = rest / KS;
    int k = ks * 32 + (lane >> 4) * 8 + j;
    int n16 = lane & 15;
    float val = 0.f;
    if (nt < NT) {
        val = W[(size_t)k * N + nt * 16 + n16];
    } else if (n16 < 8) {
        int h = n16 & 3;
        const float* av = (n16 < 4) ? as : ad;
        float s = 0.f;
        for (int c = 0; c < C; c++) s += W[(size_t)k * N + h * C + c] * av[h * C + c];
        val = s;
    }
    Wf[idx] = f2bf(val);
}

// ---------------- MFMA GEMM body + fused attention dots
template <bool AF32, int KK, int NT>
__device__ __forceinline__ void gemm_body(const void* __restrict__ Aptr,
                                          const u16* __restrict__ Wf,
                                          u16* __restrict__ Out,
                                          float* __restrict__ ssrc,
                                          float* __restrict__ sdst, int M, int bid) {
    const int KS = KK / 32;
    const int NCOL = NT * 16;
    int wid = threadIdx.x >> 6, lane = threadIdx.x & 63;
    int r0 = bid * 64 + wid * 16;
    int m = lane & 15, quad = lane >> 4;
    int row = r0 + m;
    bool rowok = row < M;

    v8s a[KS];
    if (AF32) {
        const float* ap = (const float*)Aptr + (size_t)(rowok ? row : 0) * KK + quad * 8;
        #pragma unroll
        for (int ks = 0; ks < KS; ks++) {
            if (rowok) {
                float4 fa = *(const float4*)(ap + ks * 32);
                float4 fb = *(const float4*)(ap + ks * 32 + 4);
                union { unsigned u[4]; v8s v; } c;
                c.u[0] = pk_bf16(fa.x, fa.y); c.u[1] = pk_bf16(fa.z, fa.w);
                c.u[2] = pk_bf16(fb.x, fb.y); c.u[3] = pk_bf16(fb.z, fb.w);
                a[ks] = c.v;
            } else {
                a[ks] = (v8s){0,0,0,0,0,0,0,0};
            }
        }
    } else {
        const u16* ap = (const u16*)Aptr + (size_t)(rowok ? row : 0) * KK + quad * 8;
        #pragma unroll
        for (int ks = 0; ks < KS; ks++)
            a[ks] = rowok ? *(const v8s*)(ap + ks * 32) : (v8s){0,0,0,0,0,0,0,0};
    }

    const v8s* bp0 = (const v8s*)Wf + lane;
    #pragma unroll 2
    for (int nt = 0; nt < NT; nt++) {
        v4f acc = {0.f, 0.f, 0.f, 0.f};
        const v8s* bp = bp0 + nt * KS * 64;
        #pragma unroll
        for (int ks = 0; ks < KS; ks++)
            acc = __builtin_amdgcn_mfma_f32_16x16x32_bf16(a[ks], bp[ks * 64], acc, 0, 0, 0);
        int col = nt * 16 + m;
        #pragma unroll
        for (int reg = 0; reg < 4; reg++) {
            int r = r0 + quad * 4 + reg;
            if (r < M) Out[(size_t)r * NCOL + col] = f2bf(acc[reg]);
        }
    }
    {
        v4f acc = {0.f, 0.f, 0.f, 0.f};
        const v8s* bp = bp0 + NT * KS * 64;
        #pragma unroll
        for (int ks = 0; ks < KS; ks++)
            acc = __builtin_amdgcn_mfma_f32_16x16x32_bf16(a[ks], bp[ks * 64], acc, 0, 0, 0);
        if (m < 8) {
            float* tgt = (m < 4) ? ssrc : sdst;
            int h = m & 3;
            #pragma unroll
            for (int reg = 0; reg < 4; reg++) {
                int r = r0 + quad * 4 + reg;
                if (r < M) tgt[r * 4 + h] = acc[reg];
            }
        }
    }
}

// ---------------- merged: count histogram + both weight repacks
__global__ __launch_bounds__(256) void count_repack(const int* __restrict__ ei,
                                                    int* __restrict__ counts,
                                                    const float* __restrict__ W1,
                                                    const float* __restrict__ as1,
                                                    const float* __restrict__ ad1,
                                                    u16* __restrict__ Wf1,
                                                    const float* __restrict__ W2,
                                                    const float* __restrict__ as2,
                                                    const float* __restrict__ ad2,
                                                    u16* __restrict__ Wf2) {
    int b = blockIdx.x;
    if (b < CB) {
        int t = b * 256 + threadIdx.x;
        if (t >= ETOT) return;
        int d = (t < NEDGES) ? ei[NEDGES + t] : (t - NEDGES);
        atomicAdd(&counts[d], 1);
    } else if (b < CB + RB1) {
        repack_body(W1, as1, ad1, Wf1, FIN, D1, C1, 9 * 8 * 512, (b - CB) * 256 + threadIdx.x);
    } else {
        repack_body(W2, as2, ad2, Wf2, D1, D2, C2, 11 * 4 * 512, (b - CB - RB1) * 256 + threadIdx.x);
    }
}

__global__ __launch_bounds__(1024) void scan_k(const int* __restrict__ counts, int* __restrict__ rowptr) {
    __shared__ int wsum[16];
    __shared__ int srun;
    const int t = threadIdx.x;
    const int lane = t & 63, wid = t >> 6;
    if (t == 0) srun = 0;
    __syncthreads();
    for (int base = 0; base < NNODES; base += 4096) {
        int i4 = base + t * 4;
        int4 v = make_int4(0, 0, 0, 0);
        if (i4 < NNODES) v = *(const int4*)(counts + i4);
        int tsum = v.x + v.y + v.z + v.w;
        int x = tsum;
        #pragma unroll
        for (int off = 1; off < 64; off <<= 1) {
            int y = __shfl_up(x, off, 64);
            if (lane >= off) x += y;
        }
        if (lane == 63) wsum[wid] = x;
        __syncthreads();
        if (wid == 0) {
            int w = (lane < 16) ? wsum[lane] : 0;
            #pragma unroll
            for (int off = 1; off < 16; off <<= 1) {
                int y = __shfl_up(w, off, 64);
                if (lane >= off) w += y;
            }
            if (lane < 16) wsum[lane] = w;
        }
        __syncthreads();
        int wbase = (wid > 0) ? wsum[wid - 1] : 0;
        int run = srun;
        int pre = run + wbase + x - tsum;
        if (i4 < NNODES) {
            rowptr[i4]     = pre;
            rowptr[i4 + 1] = pre + v.x;
            rowptr[i4 + 2] = pre + v.x + v.y;
            rowptr[i4 + 3] = pre + v.x + v.y + v.z;
        }
        __syncthreads();
        if (t == 1023) srun = run + wsum[15];
        __syncthreads();
    }
    if (t == 0) rowptr[NNODES] = srun;
}

// ---------------- merged: gemm1 (blocks 0..GB1-1) + CSR fill (rest)
__global__ __launch_bounds__(256) void gemm1_fill(const float* __restrict__ x,
                                                  const u16* __restrict__ Wf1,
                                                  u16* __restrict__ BH1,
                                                  float* __restrict__ ssrc,
                                                  float* __restrict__ sdst,
                                                  const int* __restrict__ ei,
                                                  const int* __restrict__ rowptr,
                                                  int* __restrict__ cursor,
                                                  u16* __restrict__ esrc) {
    if (blockIdx.x < GB1) {
        gemm_body<true, FIN, 8>(x, Wf1, BH1, ssrc, sdst, NNODES, blockIdx.x);
    } else {
        int t = (blockIdx.x - GB1) * 256 + threadIdx.x;
        if (t >= ETOT) return;
        int s, d;
        if (t < NEDGES) { s = ei[t]; d = ei[NEDGES + t]; } else { s = t - NEDGES; d = s; }
        int pos = atomicAdd(&cursor[d], 1);
        esrc[rowptr[d] + pos] = (u16)s;
    }
}

template <int KK, int NT>
__global__ __launch_bounds__(256) void gemm_mfma(const u16* __restrict__ A,
                                                 const u16* __restrict__ Wf,
                                                 u16* __restrict__ Out,
                                                 float* __restrict__ ssrc,
                                                 float* __restrict__ sdst, int M) {
    gemm_body<false, KK, NT>(A, Wf, Out, ssrc, sdst, M, blockIdx.x);
}

// phase A: 32-edge tile, head-parallel; lane = hh*16 + jj handles edges jj, jj+16.
// max-free softmax (e bounded; shift-invariance). den per head via 4-step subgroup shuffle.
#define PHASE_A32(SRC_ARR, P_ARR)                                                  \
    int nj = end - tb; if (nj > 32) nj = 32;                                       \
    bool on1 = jj < nj, on2 = jj + 16 < nj;                                        \
    int sE1 = on1 ? (int)esrc[tb + jj] : 0;                                        \
    int sE2 = on2 ? (int)esrc[tb + 16 + jj] : 0;                                   \
    if (hh == 0) { if (on1) SRC_ARR[wid][jj] = sE1;                                \
                   if (on2) SRC_ARR[wid][16 + jj] = sE2; }                         \
    float pa = on1 ? __expf(leaky(ssrc[sE1 * 4 + hh] + sdh)) : 0.f;                \
    float pb = on2 ? __expf(leaky(ssrc[sE2 * 4 + hh] + sdh)) : 0.f;                \
    float tsum = pa + pb;                                                          \
    tsum += __shfl_xor(tsum, 1, 64); tsum += __shfl_xor(tsum, 2, 64);              \
    tsum += __shfl_xor(tsum, 4, 64); tsum += __shfl_xor(tsum, 8, 64);              \
    den += tsum;                                                                   \
    if (on1) P_ARR[wid][hh][jj] = pa;                                              \
    if (on2) P_ARR[wid][hh][16 + jj] = pb;

// ---------------- layer 1: gather + softmax + bias + ELU + LN -> bf16 BOb
__global__ __launch_bounds__(256) void gat_fused1(const int* __restrict__ rowptr,
                                                  const u16* __restrict__ esrc,
                                                  const float* __restrict__ ssrc,
                                                  const float* __restrict__ sdst,
                                                  const u16* __restrict__ BH,
                                                  const float* __restrict__ b1,
                                                  const float* __restrict__ g,
                                                  const float* __restrict__ be,
                                                  u16* __restrict__ BOb) {
    __shared__ int   s_src[4][32];
    __shared__ float s_p[4][4][32];
    __shared__ float s_den[4][4];
    int wid = threadIdx.x >> 6, lane = threadIdx.x & 63;
    int node = blockIdx.x * 4 + wid;
    int jj = lane & 15, hh = lane >> 4;
    int l8 = lane & 15, grp = lane >> 4;
    int head = l8 >> 2;
    float sdh = sdst[node * 4 + hh];
    int beg = rowptr[node], end = rowptr[node + 1];
    float den = 0.f;
    float acc[8];
    #pragma unroll
    for (int i = 0; i < 8; i++) acc[i] = 0.f;

    for (int tb = beg; tb < end; tb += 32) {
        PHASE_A32(s_src, s_p)
        #pragma unroll 8
        for (int j = grp; j < nj; j += 4) {
            int sj = s_src[wid][j];
            float al = s_p[wid][head][j];
            uint4 h = *(const uint4*)(BH + (size_t)sj * D1 + l8 * 8);
            acc[0] += al * bf2f(h.x & 0xffffu); acc[1] += al * bf2f(h.x >> 16);
            acc[2] += al * bf2f(h.y & 0xffffu); acc[3] += al * bf2f(h.y >> 16);
            acc[4] += al * bf2f(h.z & 0xffffu); acc[5] += al * bf2f(h.z >> 16);
            acc[6] += al * bf2f(h.w & 0xffffu); acc[7] += al * bf2f(h.w >> 16);
        }
    }
    if (jj == 0) s_den[wid][hh] = den;
    #pragma unroll
    for (int i = 0; i < 8; i++) {
        acc[i] += __shfl_xor(acc[i], 16, 64);
        acc[i] += __shfl_xor(acc[i], 32, 64);
    }
    float rden = 1.f / s_den[wid][head];
    float4 bA = *(const float4*)(b1 + l8 * 8), bB = *(const float4*)(b1 + l8 * 8 + 4);
    float v[8];
    v[0] = acc[0] * rden + bA.x; v[1] = acc[1] * rden + bA.y;
    v[2] = acc[2] * rden + bA.z; v[3] = acc[3] * rden + bA.w;
    v[4] = acc[4] * rden + bB.x; v[5] = acc[5] * rden + bB.y;
    v[6] = acc[6] * rden + bB.z; v[7] = acc[7] * rden + bB.w;
    float s8 = 0.f, q8 = 0.f;
    #pragma unroll
    for (int i = 0; i < 8; i++) {
        v[i] = v[i] > 0.f ? v[i] : __expf(v[i]) - 1.f;
        s8 += v[i]; q8 += v[i] * v[i];
    }
    wave_sum2(s8, q8);                              // chans counted 4x -> /512
    float mu = s8 * (1.f / 512.f);
    float var = q8 * (1.f / 512.f) - mu * mu;
    float rs = rsqrtf(var + 1e-5f);
    if (grp == 0) {
        float4 gA = *(const float4*)(g + l8 * 8),  gB = *(const float4*)(g + l8 * 8 + 4);
        float4 eA = *(const float4*)(be + l8 * 8), eB = *(const float4*)(be + l8 * 8 + 4);
        u16 o[8] = {f2bf((v[0] - mu) * rs * gA.x + eA.x), f2bf((v[1] - mu) * rs * gA.y + eA.y),
                    f2bf((v[2] - mu) * rs * gA.z + eA.z), f2bf((v[3] - mu) * rs * gA.w + eA.w),
                    f2bf((v[4] - mu) * rs * gB.x + eB.x), f2bf((v[5] - mu) * rs * gB.y + eB.y),
                    f2bf((v[6] - mu) * rs * gB.z + eB.z), f2bf((v[7] - mu) * rs * gB.w + eB.w)};
        *(uint4*)(BOb + (size_t)node * D1 + l8 * 8) = *(uint4*)o;
    }
}

// ---------------- layer 2: gather + softmax + head-mean + LN + log_softmax -> f32 out
__global__ __launch_bounds__(256) void gat_fused2(const int* __restrict__ rowptr,
                                                  const u16* __restrict__ esrc,
                                                  const float* __restrict__ ssrc,
                                                  const float* __restrict__ sdst,
                                                  const u16* __restrict__ BH,
                                                  const float* __restrict__ b2,
                                                  const float* __restrict__ g,
                                                  const float* __restrict__ be,
                                                  float* __restrict__ out) {
    __shared__ int   s_src[4][32];
    __shared__ float s_p[4][4][32];
    __shared__ float s_den[4][4];
    __shared__ float scr3[4][3][160];
    int wid = threadIdx.x >> 6, lane = threadIdx.x & 63;
    int node = blockIdx.x * 4 + wid;
    int jj = lane & 15, hh = lane >> 4;
    int grp = lane / 20;                    // 3 => idle in phase B
    int glane = lane - grp * 20;
    int head = glane / 5;
    float sdh = sdst[node * 4 + hh];
    int beg = rowptr[node], end = rowptr[node + 1];
    float den = 0.f;
    float acc[8];
    #pragma unroll
    for (int i = 0; i < 8; i++) acc[i] = 0.f;

    for (int tb = beg; tb < end; tb += 32) {
        PHASE_A32(s_src, s_p)
        if (grp < 3) {
            #pragma unroll 4
            for (int j = grp; j < nj; j += 3) {
                int sj = s_src[wid][j];
                float al = s_p[wid][head][j];
                uint4 h = *(const uint4*)(BH + (size_t)sj * D2 + glane * 8);
                acc[0] += al * bf2f(h.x & 0xffffu); acc[1] += al * bf2f(h.x >> 16);
                acc[2] += al * bf2f(h.y & 0xffffu); acc[3] += al * bf2f(h.y >> 16);
                acc[4] += al * bf2f(h.z & 0xffffu); acc[5] += al * bf2f(h.z >> 16);
                acc[6] += al * bf2f(h.w & 0xffffu); acc[7] += al * bf2f(h.w >> 16);
            }
        }
    }
    if (jj == 0) s_den[wid][hh] = den;
    if (grp < 3) {
        float rden = 1.f / s_den[wid][head];
        float4 oA = {acc[0] * rden, acc[1] * rden, acc[2] * rden, acc[3] * rden};
        float4 oB = {acc[4] * rden, acc[5] * rden, acc[6] * rden, acc[7] * rden};
        *(float4*)&scr3[wid][grp][glane * 8]     = oA;
        *(float4*)&scr3[wid][grp][glane * 8 + 4] = oB;
    }
    bool act = lane < 40;
    int c = act ? lane : 0;
    float o = 0.f;
    if (act) {
        float s = 0.f;
        #pragma unroll
        for (int k = 0; k < 4; k++)
            #pragma unroll
            for (int gg = 0; gg < 3; gg++) s += scr3[wid][gg][c + 40 * k];
        o = 0.25f * s + b2[c];
    }
    float so = act ? o : 0.f, qo = so * o;
    wave_sum2(so, qo);
    float mu = so * (1.f / 40.f);
    float var = qo * (1.f / 40.f) - mu * mu;
    float rs = rsqrtf(var + 1e-5f);
    // y bounded by sqrt(40)*|g|+|be| -> exp safe without max-subtraction
    float y = act ? (o - mu) * rs * g[c] + be[c] : 0.f;
    float ex = act ? __expf(y) : 0.f;
    float lse = __logf(wave_sum(ex));
    if (act) out[(size_t)node * 40 + c] = y - lse;
}

extern "C" void kernel_launch(void* const* d_in, const int* in_sizes, int n_in,
                              void* d_out, int out_size, void* d_ws, size_t ws_size,
                              hipStream_t stream) {
    const float* x   = (const float*)d_in[0];
    const int*   ei  = (const int*)d_in[1];
    const float* W1  = (const float*)d_in[2];
    const float* as1 = (const float*)d_in[3];
    const float* ad1 = (const float*)d_in[4];
    const float* b1  = (const float*)d_in[5];
    const float* W2  = (const float*)d_in[6];
    const float* as2 = (const float*)d_in[7];
    const float* ad2 = (const float*)d_in[8];
    const float* b2  = (const float*)d_in[9];
    const float* g0  = (const float*)d_in[10];
    const float* be0 = (const float*)d_in[11];
    const float* g1  = (const float*)d_in[12];
    const float* be1 = (const float*)d_in[13];

    float* ws = (float*)d_ws;
    u16*   BH1    = (u16*)ws;                       // 50000*128 bf16 = 3,200,000 f
    u16*   BH2    = (u16*)(ws + 3200000);           // 50000*160 bf16 = 4,000,000 f
    u16*   BOb    = (u16*)(ws + 7200000);           // 50000*128 bf16 = 3,200,000 f
    float* ssrc   = ws + 10400000;                  // 200,000 f
    float* sdst   = ws + 10600000;                  // 200,000 f
    int*   rowptr = (int*)(ws + 10800000);          // 50,001 (+3 pad)
    u16*   esrc   = (u16*)(ws + 10850004);          // ETOT u16 = 425,000 f
    int*   counts = (int*)(ws + 11275004);          // 50,000
    int*   cursor = (int*)(ws + 11325004);          // 50,000 (contiguous with counts)
    u16*   Wf1    = (u16*)(ws + 11375004);          // 36,864 bf16
    u16*   Wf2    = (u16*)(ws + 11393436);          // 22,528 bf16

    const int nb4 = NNODES / 4;

    hipMemsetAsync(counts, 0, 2 * NNODES * sizeof(int), stream);
    count_repack<<<CB + RB1 + RB2, 256, 0, stream>>>(ei, counts, W1, as1, ad1, Wf1,
                                                     W2, as2, ad2, Wf2);
    scan_k<<<1, 1024, 0, stream>>>(counts, rowptr);
    gemm1_fill<<<GB1 + CB, 256, 0, stream>>>(x, Wf1, BH1, ssrc, sdst, ei, rowptr, cursor, esrc);
    gat_fused1<<<nb4, 256, 0, stream>>>(rowptr, esrc, ssrc, sdst, BH1, b1, g0, be0, BOb);
    gemm_mfma<D1, 10><<<GB1, 256, 0, stream>>>(BOb, Wf2, BH2, ssrc, sdst, NNODES);
    gat_fused2<<<nb4, 256, 0, stream>>>(rowptr, esrc, ssrc, sdst, BH2, b2, g1, be1, (float*)d_out);
}